// Round 4
// baseline (8530.067 us; speedup 1.0000x reference)
//
#include <hip/hip_runtime.h>
#include <math.h>

typedef __attribute__((ext_vector_type(8))) short bf16x8;
typedef __attribute__((ext_vector_type(4))) float f32x4;
typedef __attribute__((ext_vector_type(8))) _Float16 f16x8;
typedef __attribute__((ext_vector_type(4))) _Float16 f16x4;
typedef unsigned short ushort_t;

#define T_STEPS 64
#define BATCH   64
#define VOCAB   32000
#define EMB     512
#define HID     1024
#define G4      4096

__device__ __forceinline__ unsigned short f2bf(float x) {
    unsigned u = __builtin_bit_cast(unsigned, x);
    u += 0x7FFFu + ((u >> 16) & 1u);
    return (unsigned short)(u >> 16);
}
__device__ __forceinline__ float bf2f(unsigned short h) {
    unsigned u = ((unsigned)h) << 16;
    return __builtin_bit_cast(float, u);
}
__device__ __forceinline__ unsigned pack2(unsigned short a, unsigned short b) {
    return (unsigned)a | ((unsigned)b << 16);
}

// packed A-fragment offset for 16x16x32 MFMA: element (row, k) ->
// ((k>>5)*M16 + (row>>4))*512 + ((k&31)>>3)*128 + (row&15)*8 + (k&7)
__device__ __forceinline__ size_t packA_off(int row, int k, int M16) {
    return ((size_t)((k >> 5) * M16 + (row >> 4))) * 512 +
           ((k & 31) >> 3) * 128 + (row & 15) * 8 + (k & 7);
}

// ---------------------------------------------------------------------------
// fp16 single-term MFMA GEMM (for emb and z0x). B scaled at conversion.
// ---------------------------------------------------------------------------
template<int BM, int BN, int NW_M, int NW_N>
__launch_bounds__(NW_M * NW_N * 64)
__global__ void gemm_f16s(const float* __restrict__ A, const float* __restrict__ B,
                          float* __restrict__ C, int lda, int ldb, int ldc,
                          int KCHUNK, size_t chunkStride, float scale, float invScale) {
    constexpr int THREADS = NW_M * NW_N * 64;
    constexpr int MF = BM / NW_M / 16;
    constexpr int NF = BN / NW_N / 16;
    __shared__ _Float16 AhS[BM][40];
    __shared__ _Float16 BhS[BN][40];

    const int tid  = threadIdx.x;
    const int row0 = blockIdx.y * BM;
    const int col0 = blockIdx.x * BN;
    const int kBeg = blockIdx.z * KCHUNK;
    C += (size_t)blockIdx.z * chunkStride;

    const int l = tid & 63, w = tid >> 6;
    const int wm = w / NW_N, wn = w % NW_N;
    const int lr = l & 15, lk = l >> 4;

    f32x4 acc[MF][NF];
#pragma unroll
    for (int m = 0; m < MF; ++m)
#pragma unroll
        for (int n = 0; n < NF; ++n)
#pragma unroll
            for (int r = 0; r < 4; ++r) acc[m][n][r] = 0.f;

    constexpr int AI = BM * 4 / THREADS;       // A units (8 elems each)
    constexpr int KG = THREADS / BN;           // k4-groups per B pass
    constexpr int BI = 8 / KG;

    for (int k0 = 0; k0 < KCHUNK; k0 += 32) {
#pragma unroll
        for (int i = 0; i < AI; ++i) {
            int f = tid + i * THREADS;
            int r = f >> 2, k8 = (f & 3) << 3;
            const float* ap = A + (size_t)(row0 + r) * lda + kBeg + k0 + k8;
            float4 v0 = *(const float4*)ap;
            float4 v1 = *(const float4*)(ap + 4);
            f16x8 hv;
            hv[0] = (_Float16)v0.x; hv[1] = (_Float16)v0.y;
            hv[2] = (_Float16)v0.z; hv[3] = (_Float16)v0.w;
            hv[4] = (_Float16)v1.x; hv[5] = (_Float16)v1.y;
            hv[6] = (_Float16)v1.z; hv[7] = (_Float16)v1.w;
            *(f16x8*)&AhS[r][k8] = hv;
        }
#pragma unroll
        for (int i = 0; i < BI; ++i) {
            int n  = tid & (BN - 1);
            int kg = tid / BN;
            int k  = (i * KG + kg) << 2;
            const float* bp = B + (size_t)(kBeg + k0 + k) * ldb + col0 + n;
            f16x4 bv;
            bv[0] = (_Float16)(bp[0] * scale);
            bv[1] = (_Float16)(bp[(size_t)ldb] * scale);
            bv[2] = (_Float16)(bp[2 * (size_t)ldb] * scale);
            bv[3] = (_Float16)(bp[3 * (size_t)ldb] * scale);
            *(f16x4*)&BhS[n][k] = bv;
        }
        __syncthreads();
        f16x8 a[MF], b[NF];
#pragma unroll
        for (int m = 0; m < MF; ++m)
            a[m] = *(const f16x8*)&AhS[wm * MF * 16 + m * 16 + lr][lk * 8];
#pragma unroll
        for (int n = 0; n < NF; ++n)
            b[n] = *(const f16x8*)&BhS[wn * NF * 16 + n * 16 + lr][lk * 8];
#pragma unroll
        for (int m = 0; m < MF; ++m)
#pragma unroll
            for (int n = 0; n < NF; ++n)
                acc[m][n] = __builtin_amdgcn_mfma_f32_16x16x32_f16(a[m], b[n], acc[m][n], 0, 0, 0);
        __syncthreads();
    }

#pragma unroll
    for (int n = 0; n < NF; ++n) {
        int col = col0 + wn * NF * 16 + n * 16 + lr;
#pragma unroll
        for (int m = 0; m < MF; ++m) {
            int rbase = row0 + wm * MF * 16 + m * 16 + lk * 4;
#pragma unroll
            for (int r = 0; r < 4; ++r)
                C[(size_t)(rbase + r) * ldc + col] = acc[m][n][r] * invScale;
        }
    }
}

// sum 8 split-K partials
__global__ void reduce8(const float* __restrict__ zp, float* __restrict__ out, size_t cs) {
    size_t i = ((size_t)blockIdx.x * 256 + threadIdx.x) * 4;
    float4 a = *(const float4*)(zp + i);
#pragma unroll
    for (int c = 1; c < 8; ++c) {
        float4 b = *(const float4*)(zp + c * cs + i);
        a.x += b.x; a.y += b.y; a.z += b.z; a.w += b.w;
    }
    *(float4*)(out + i) = a;
}

// ---------------------------------------------------------------------------
// Weight preconversion (unchanged layout, verified round 3).
// ---------------------------------------------------------------------------
__launch_bounds__(256)
__global__ void wconvert(const float* __restrict__ W, ushort_t* __restrict__ Wh,
                         ushort_t* __restrict__ Wl, int Krows) {
    __shared__ float tile[32][33];
    const int k0 = blockIdx.x * 32;
    const int n0 = blockIdx.y * 32;
    const int tid = threadIdx.x;
#pragma unroll
    for (int i = 0; i < 4; ++i) {
        int idx = tid + i * 256;
        int r = idx >> 5, c = idx & 31;
        tile[r][c] = W[(size_t)(k0 + r) * 4096 + n0 + c];
    }
    __syncthreads();
    const int rn = tid >> 3;
    const int cq = (tid & 7) * 4;
    unsigned short h[4], lo[4];
#pragma unroll
    for (int j = 0; j < 4; ++j) {
        float v = tile[cq + j][rn];
        h[j]  = f2bf(v);
        lo[j] = f2bf(v - bf2f(h[j]));
    }
    const int n = n0 + rn;
    const int g = n >> 4, rr = n & 15;
    const int k = k0 + cq;
    const int K8 = Krows >> 3;
    size_t off = ((size_t)g * K8 + (k >> 3)) * 128 + rr * 8 + (k & 7);
    uint2 hp; hp.x = pack2(h[0], h[1]);  hp.y = pack2(h[2], h[3]);
    uint2 lp; lp.x = pack2(lo[0], lo[1]); lp.y = pack2(lo[2], lo[3]);
    *(uint2*)(Wh + off) = hp;
    *(uint2*)(Wl + off) = lp;
}

// ---------------------------------------------------------------------------
// Fused LSTM layer-step: one dispatch. 256 blocks x 16 z-cols, full K,
// 4-wave split-K + LDS reduce; atomic last-block finisher applies the
// activation for its 16 hidden units and writes packed h planes.
// ---------------------------------------------------------------------------
__launch_bounds__(256)
__global__ void lstm_step(const ushort_t* __restrict__ Ah, const ushort_t* __restrict__ Al,
                          const ushort_t* __restrict__ Wh, const ushort_t* __restrict__ Wl,
                          int k32pw, const float* __restrict__ xpart,
                          const float* __restrict__ bias,
                          float* __restrict__ c_state, float* __restrict__ histF,
                          float* __restrict__ zfull, unsigned* __restrict__ cnt,
                          ushort_t* __restrict__ d1h, ushort_t* __restrict__ d1l, int kofs1,
                          ushort_t* __restrict__ d2h, ushort_t* __restrict__ d2l, int kofs2) {
    __shared__ float red[4096];
    __shared__ int flag;
    const int tid = threadIdx.x, cg = blockIdx.x;
    const int l = tid & 63, w = tid >> 6;
    const int lr = l & 15, lk = l >> 4;
    const int K8 = k32pw * 16;                         // K/8
    const size_t wbase = (size_t)cg * K8 * 128 + lk * 128 + lr * 8;

    f32x4 acc[4];
#pragma unroll
    for (int m = 0; m < 4; ++m)
#pragma unroll
        for (int r = 0; r < 4; ++r) acc[m][r] = 0.f;

    const int s0 = w * k32pw;
    for (int s = s0; s < s0 + k32pw; ++s) {
        bf16x8 bh = *(const bf16x8*)(Wh + wbase + (size_t)s * 512);
        bf16x8 bl = *(const bf16x8*)(Wl + wbase + (size_t)s * 512);
#pragma unroll
        for (int m = 0; m < 4; ++m) {
            size_t ao = (size_t)(s * 4 + m) * 512 + l * 8;
            bf16x8 ah = *(const bf16x8*)(Ah + ao);
            bf16x8 al = *(const bf16x8*)(Al + ao);
            acc[m] = __builtin_amdgcn_mfma_f32_16x16x32_bf16(ah, bh, acc[m], 0, 0, 0);
            acc[m] = __builtin_amdgcn_mfma_f32_16x16x32_bf16(al, bh, acc[m], 0, 0, 0);
            acc[m] = __builtin_amdgcn_mfma_f32_16x16x32_bf16(ah, bl, acc[m], 0, 0, 0);
        }
    }
#pragma unroll
    for (int m = 0; m < 4; ++m)
        *(f32x4*)&red[(w * 64 + l) * 16 + m * 4] = acc[m];
    __syncthreads();

    // write z for our 16 columns (bias + xpart added here)
    {
        const int r = tid >> 2;                 // row 0..63
        const int c0 = (tid & 3) << 2;          // col 0,4,8,12
        const int m = r >> 4, lkr = (r >> 2) & 3, reg = r & 3;
        float4 zv;
        float* zvp = &zv.x;
#pragma unroll
        for (int j = 0; j < 4; ++j) {
            int c = c0 + j;
            float v = 0.f;
#pragma unroll
            for (int ww = 0; ww < 4; ++ww)
                v += red[(ww * 64 + c + (lkr << 4)) * 16 + m * 4 + reg];
            int n = cg * 16 + c;
            v += bias[n];
            if (xpart) v += xpart[(size_t)r * 4096 + n];
            zvp[j] = v;
        }
        *(float4*)(zfull + (size_t)r * 4096 + cg * 16 + c0) = zv;
    }
    __threadfence();
    __syncthreads();
    const int hg = cg & 63;
    if (tid == 0) {
        unsigned old = atomicAdd(cnt + hg, 1u);
        flag = (old == 3u);
    }
    __syncthreads();
    if (!flag) return;
    __threadfence();

    // finisher: activation for hidden units [hg*16, hg*16+16), all 64 rows
    {
        const int r = tid >> 2;
        const int c0 = (tid & 3) << 2;
        const int n0 = hg * 16 + c0;
        float4 zf = *(const float4*)(zfull + (size_t)r * 4096 + n0);
        float4 zi = *(const float4*)(zfull + (size_t)r * 4096 + n0 + 1024);
        float4 zo = *(const float4*)(zfull + (size_t)r * 4096 + n0 + 2048);
        float4 zg = *(const float4*)(zfull + (size_t)r * 4096 + n0 + 3072);
        float4 cv = *(const float4*)(c_state + (size_t)r * 1024 + n0);
        float hn[4];
        const float* zfp = &zf.x; const float* zip = &zi.x;
        const float* zop = &zo.x; const float* zgp = &zg.x;
        float* cvp = &cv.x;
#pragma unroll
        for (int j = 0; j < 4; ++j) {
            float f = 1.f / (1.f + expf(-zfp[j]));
            float i = 1.f / (1.f + expf(-zip[j]));
            float o = 1.f / (1.f + expf(-zop[j]));
            float g = tanhf(zgp[j]);
            float cn = f * cvp[j] + i * g;
            cvp[j] = cn;
            hn[j] = o * tanhf(cn);
        }
        *(float4*)(c_state + (size_t)r * 1024 + n0) = cv;
        *(float4*)(histF + (size_t)r * 1024 + n0) = *(float4*)hn;
        unsigned short hh[4], hl[4];
#pragma unroll
        for (int j = 0; j < 4; ++j) {
            hh[j] = f2bf(hn[j]);
            hl[j] = f2bf(hn[j] - bf2f(hh[j]));
        }
        uint2 hp; hp.x = pack2(hh[0], hh[1]); hp.y = pack2(hh[2], hh[3]);
        uint2 lp; lp.x = pack2(hl[0], hl[1]); lp.y = pack2(hl[2], hl[3]);
        size_t o1 = packA_off(r, kofs1 + n0, 4);
        *(uint2*)(d1h + o1) = hp;
        *(uint2*)(d1l + o1) = lp;
        if (d2h) {
            size_t o2 = packA_off(r, kofs2 + n0, 4);
            *(uint2*)(d2h + o2) = hp;
            *(uint2*)(d2l + o2) = lp;
        }
    }
    __threadfence();
    if (tid == 0) cnt[hg] = 0;
}

// ---------------------------------------------------------------------------
// gates + gating; emits gated as packed bf16 hi/lo A-fragment planes.
// ---------------------------------------------------------------------------
__launch_bounds__(256)
__global__ void gates_gated(const float* __restrict__ h0s, const float* __restrict__ h1s,
                            const float* __restrict__ gw,
                            ushort_t* __restrict__ gAh, ushort_t* __restrict__ gAl) {
    const int r = blockIdx.x;
    const int tid = threadIdx.x;
    const float* h0r = h0s + (size_t)r * HID;
    const float* h1r = h1s + (size_t)r * HID;
    float p0 = 0.f, p1 = 0.f;
    for (int k = tid; k < HID; k += 256) {
        float v0 = h0r[k], v1 = h1r[k];
        p0 += v0 * gw[2 * k]     + v1 * gw[2 * (HID + k)];
        p1 += v0 * gw[2 * k + 1] + v1 * gw[2 * (HID + k) + 1];
    }
#pragma unroll
    for (int off = 32; off; off >>= 1) {
        p0 += __shfl_down(p0, off);
        p1 += __shfl_down(p1, off);
    }
    __shared__ float s0[4], s1[4];
    __shared__ float gg[2];
    if ((tid & 63) == 0) { s0[tid >> 6] = p0; s1[tid >> 6] = p1; }
    __syncthreads();
    if (tid == 0) {
        float a = s0[0] + s0[1] + s0[2] + s0[3];
        float b = s1[0] + s1[1] + s1[2] + s1[3];
        gg[0] = 1.f / (1.f + expf(-a));
        gg[1] = 1.f / (1.f + expf(-b));
    }
    __syncthreads();
    float g0 = gg[0], g1 = gg[1];
    const int n0 = tid * 4;
    float v[4]; unsigned short hh[4], hl[4];
#pragma unroll
    for (int j = 0; j < 4; ++j) {
        int n = n0 + j;
        v[j] = g0 * h0r[n] + g1 * h1r[n];
        hh[j] = f2bf(v[j]);
        hl[j] = f2bf(v[j] - bf2f(hh[j]));
    }
    uint2 hp; hp.x = pack2(hh[0], hh[1]); hp.y = pack2(hh[2], hh[3]);
    uint2 lp; lp.x = pack2(hl[0], hl[1]); lp.y = pack2(hl[2], hl[3]);
    size_t off = packA_off(r, n0, 256);
    *(uint2*)(gAh + off) = hp;
    *(uint2*)(gAl + off) = lp;
}

// ---------------------------------------------------------------------------
// logits GEMM: A from packed bf16 hi/lo planes (pure copy to LDS), B (outw)
// converted in LDS; BM=256 x BN=128, 8 waves, 3-term bf16 MFMA, XCD swizzle.
// ---------------------------------------------------------------------------
__launch_bounds__(512)
__global__ void gemm_out(const ushort_t* __restrict__ gAh, const ushort_t* __restrict__ gAl,
                         const float* __restrict__ Bsrc, const float* __restrict__ bias,
                         float* __restrict__ C) {
    __shared__ ushort_t AhL[8192], AlL[8192];
    __shared__ ushort_t BhS[128][40], BlS[128][40];

    const int tid = threadIdx.x;
    int lin = blockIdx.y * 250 + blockIdx.x;
    int slin = (lin & 7) * 500 + (lin >> 3);      // 4000 % 8 == 0 -> bijective
    const int bi = slin / 250, bj = slin % 250;
    const int row0 = bi * 256, col0 = bj * 128;

    const int l = tid & 63, w = tid >> 6;
    const int wm = w >> 1, wn = w & 1;
    const int lr = l & 15, lk = l >> 4;

    f32x4 acc[4][4];
#pragma unroll
    for (int m = 0; m < 4; ++m)
#pragma unroll
        for (int n = 0; n < 4; ++n)
#pragma unroll
            for (int r = 0; r < 4; ++r) acc[m][n][r] = 0.f;

    for (int k32 = 0; k32 < 32; ++k32) {
        // ---- stage A: linear copy of 2 x 16KB packed fragments ----
        const size_t chunk = ((size_t)(k32 * 256 + bi * 16)) * 512;
#pragma unroll
        for (int i = 0; i < 2; ++i) {
            int so = i * 4096 + tid * 8;
            *(uint4*)&AhL[so] = *(const uint4*)(gAh + chunk + so);
            *(uint4*)&AlL[so] = *(const uint4*)(gAl + chunk + so);
        }
        // ---- stage B: 32 x 128 fp32 -> hi/lo bf16 (coalesced) ----
#pragma unroll
        for (int i = 0; i < 2; ++i) {
            int n  = tid & 127;
            int kg = (tid >> 7) & 3;
            int k  = (i * 4 + kg) << 2;
            const float* bp = Bsrc + (size_t)(k32 * 32 + k) * VOCAB + col0 + n;
            unsigned short hh[4], hl[4];
#pragma unroll
            for (int j = 0; j < 4; ++j) {
                float v = bp[(size_t)j * VOCAB];
                hh[j] = f2bf(v);
                hl[j] = f2bf(v - bf2f(hh[j]));
            }
            uint2 hp; hp.x = pack2(hh[0], hh[1]); hp.y = pack2(hh[2], hh[3]);
            uint2 lp; lp.x = pack2(hl[0], hl[1]); lp.y = pack2(hl[2], hl[3]);
            *(uint2*)&BhS[n][k] = hp;
            *(uint2*)&BlS[n][k] = lp;
        }
        __syncthreads();
        bf16x8 ah[4], al[4], bh[4], bl[4];
#pragma unroll
        for (int m = 0; m < 4; ++m) {
            int so = (wm * 4 + m) * 512 + l * 8;
            ah[m] = *(const bf16x8*)&AhL[so];
            al[m] = *(const bf16x8*)&AlL[so];
        }
#pragma unroll
        for (int n = 0; n < 4; ++n) {
            bh[n] = *(const bf16x8*)&BhS[wn * 64 + n * 16 + lr][lk * 8];
            bl[n] = *(const bf16x8*)&BlS[wn * 64 + n * 16 + lr][lk * 8];
        }
#pragma unroll
        for (int m = 0; m < 4; ++m)
#pragma unroll
            for (int n = 0; n < 4; ++n) {
                acc[m][n] = __builtin_amdgcn_mfma_f32_16x16x32_bf16(ah[m], bh[n], acc[m][n], 0, 0, 0);
                acc[m][n] = __builtin_amdgcn_mfma_f32_16x16x32_bf16(al[m], bh[n], acc[m][n], 0, 0, 0);
                acc[m][n] = __builtin_amdgcn_mfma_f32_16x16x32_bf16(ah[m], bl[n], acc[m][n], 0, 0, 0);
            }
        __syncthreads();
    }

#pragma unroll
    for (int n = 0; n < 4; ++n) {
        int col = col0 + wn * 64 + n * 16 + lr;
        float bv = bias[col];
#pragma unroll
        for (int m = 0; m < 4; ++m) {
            int rbase = row0 + wm * 64 + m * 16 + lk * 4;
#pragma unroll
            for (int r = 0; r < 4; ++r)
                C[(size_t)(rbase + r) * VOCAB + col] = acc[m][n][r] + bv;
        }
    }
}

// ---------------------------------------------------------------------------
extern "C" void kernel_launch(void* const* d_in, const int* in_sizes, int n_in,
                              void* d_out, int out_size, void* d_ws, size_t ws_size,
                              hipStream_t stream) {
    const float* inputs = (const float*)d_in[0];
    const float* embm   = (const float*)d_in[1];
    const float* w0     = (const float*)d_in[2];
    const float* b0     = (const float*)d_in[3];
    const float* w1     = (const float*)d_in[4];
    const float* b1     = (const float*)d_in[5];
    const float* gw     = (const float*)d_in[6];
    const float* outw   = (const float*)d_in[7];
    const float* outb   = (const float*)d_in[8];
    float* logits = (float*)d_out;

    // ---- workspace layout (floats) ----
    float* ws    = (float*)d_ws;
    float* emb   = ws;                          // 2,097,152
    float* h0s   = ws + 2097152;                // 4,194,304
    float* h1s   = ws + 6291456;                // 4,194,304
    ushort_t* gAh = (ushort_t*)(ws + 10485760); // 4,194,304 shorts
    ushort_t* gAl = (ushort_t*)(ws + 12582912);
    float* zfull = ws + 14680064;               // 262,144
    float* c0    = ws + 14942208;               // 65,536
    float* c1    = ws + 15007744;               // 65,536
    ushort_t* hpB = (ushort_t*)(ws + 15073280); // 786,432 shorts (393,216 f)
    unsigned* cnt = (unsigned*)(ws + 15466496); // 64

    ushort_t* hp0h[2] = { hpB,            hpB + 65536 };
    ushort_t* hp0l[2] = { hpB + 131072,   hpB + 196608 };
    ushort_t* hp1h[2] = { hpB + 262144,   hpB + 393216 };
    ushort_t* hp1l[2] = { hpB + 524288,   hpB + 655360 };

    // ---- d_out doubles as scratch before logits ----
    float* zpEmb = (float*)d_out;                            // 8 x 2,097,152
    float* z0x   = (float*)d_out + 16777216;                 // 16,777,216
    ushort_t* wt0h = (ushort_t*)((float*)d_out + 33554432);
    ushort_t* wt0l = wt0h + 4194304;
    ushort_t* wt1h = wt0l + 4194304;
    ushort_t* wt1l = wt1h + 8388608;

    // zero c0,c1,hp,cnt (contiguous)
    hipMemsetAsync(c0, 0, (size_t)524352 * sizeof(float), stream);

    // emb = inputs @ embm, split-K x8, fp16 single (B scaled x256)
    gemm_f16s<128, 512, 2, 4><<<dim3(1, 32, 8), 512, 0, stream>>>(
        inputs, embm, zpEmb, VOCAB, EMB, EMB, VOCAB / 8, (size_t)4096 * EMB, 256.f, 1.f / 256.f);
    reduce8<<<2048, 256, 0, stream>>>(zpEmb, emb, (size_t)4096 * EMB);

    // preconvert LSTM weights
    wconvert<<<dim3(32, 128), 256, 0, stream>>>(w0 + (size_t)512 * G4, wt0h, wt0l, 1024);
    wconvert<<<dim3(64, 128), 256, 0, stream>>>(w1, wt1h, wt1l, 2048);

    // z0x = emb @ w0[:512,:], fp16 single
    gemm_f16s<128, 128, 2, 2><<<dim3(32, 32, 1), 256, 0, stream>>>(
        emb, w0, z0x, EMB, G4, G4, EMB, 0, 256.f, 1.f / 256.f);

    // sequential LSTM: 128 fused dispatches
    for (int t = 0; t < T_STEPS; ++t) {
        int p = t & 1, q = (t + 1) & 1;
        lstm_step<<<256, 256, 0, stream>>>(
            hp0h[p], hp0l[p], wt0h, wt0l, 8,
            z0x + (size_t)t * 262144, b0, c0, h0s + (size_t)t * 65536,
            zfull, cnt, hp0h[q], hp0l[q], 0, hp1h[p], hp1l[p], 0);
        lstm_step<<<256, 256, 0, stream>>>(
            hp1h[p], hp1l[p], wt1h, wt1l, 16,
            nullptr, b1, c1, h1s + (size_t)t * 65536,
            zfull, cnt, hp1h[q], hp1l[q], 1024, nullptr, nullptr, 0);
    }

    // gating -> packed bf16 hi/lo A planes
    gates_gated<<<4096, 256, 0, stream>>>(h0s, h1s, gw, gAh, gAl);

    // logits = gated @ outw + outb
    gemm_out<<<dim3(250, 16), 512, 0, stream>>>(gAh, gAl, outw, outb, logits);
}

// Round 5
// 3351.772 us; speedup vs baseline: 2.5449x; 2.5449x over previous
//
#include <hip/hip_runtime.h>
#include <math.h>

typedef __attribute__((ext_vector_type(8))) short bf16x8;
typedef __attribute__((ext_vector_type(4))) float f32x4;
typedef __attribute__((ext_vector_type(8))) _Float16 f16x8;
typedef __attribute__((ext_vector_type(4))) _Float16 f16x4;
typedef unsigned short ushort_t;

#define T_STEPS 64
#define BATCH   64
#define VOCAB   32000
#define EMB     512
#define HID     1024
#define G4      4096

__device__ __forceinline__ unsigned short f2bf(float x) {
    unsigned u = __builtin_bit_cast(unsigned, x);
    u += 0x7FFFu + ((u >> 16) & 1u);
    return (unsigned short)(u >> 16);
}
__device__ __forceinline__ float bf2f(unsigned short h) {
    unsigned u = ((unsigned)h) << 16;
    return __builtin_bit_cast(float, u);
}
__device__ __forceinline__ unsigned pack2(unsigned short a, unsigned short b) {
    return (unsigned)a | ((unsigned)b << 16);
}

// packed A-fragment offset for 16x16x32 MFMA: element (row, k) ->
// ((k>>5)*M16 + (row>>4))*512 + ((k&31)>>3)*128 + (row&15)*8 + (k&7)
__device__ __forceinline__ size_t packA_off(int row, int k, int M16) {
    return ((size_t)((k >> 5) * M16 + (row >> 4))) * 512 +
           ((k & 31) >> 3) * 128 + (row & 15) * 8 + (k & 7);
}

// ---------------------------------------------------------------------------
// fp16 single-term MFMA GEMM (for emb and z0x). B scaled at conversion.
// ---------------------------------------------------------------------------
template<int BM, int BN, int NW_M, int NW_N>
__launch_bounds__(NW_M * NW_N * 64)
__global__ void gemm_f16s(const float* __restrict__ A, const float* __restrict__ B,
                          float* __restrict__ C, int lda, int ldb, int ldc,
                          int KCHUNK, size_t chunkStride, float scale, float invScale) {
    constexpr int THREADS = NW_M * NW_N * 64;
    constexpr int MF = BM / NW_M / 16;
    constexpr int NF = BN / NW_N / 16;
    __shared__ _Float16 AhS[BM][40];
    __shared__ _Float16 BhS[BN][40];

    const int tid  = threadIdx.x;
    const int row0 = blockIdx.y * BM;
    const int col0 = blockIdx.x * BN;
    const int kBeg = blockIdx.z * KCHUNK;
    C += (size_t)blockIdx.z * chunkStride;

    const int l = tid & 63, w = tid >> 6;
    const int wm = w / NW_N, wn = w % NW_N;
    const int lr = l & 15, lk = l >> 4;

    f32x4 acc[MF][NF];
#pragma unroll
    for (int m = 0; m < MF; ++m)
#pragma unroll
        for (int n = 0; n < NF; ++n)
#pragma unroll
            for (int r = 0; r < 4; ++r) acc[m][n][r] = 0.f;

    constexpr int AI = BM * 4 / THREADS;       // A units (8 elems each)
    constexpr int KG = THREADS / BN;           // k4-groups per B pass
    constexpr int BI = 8 / KG;

    for (int k0 = 0; k0 < KCHUNK; k0 += 32) {
#pragma unroll
        for (int i = 0; i < AI; ++i) {
            int f = tid + i * THREADS;
            int r = f >> 2, k8 = (f & 3) << 3;
            const float* ap = A + (size_t)(row0 + r) * lda + kBeg + k0 + k8;
            float4 v0 = *(const float4*)ap;
            float4 v1 = *(const float4*)(ap + 4);
            f16x8 hv;
            hv[0] = (_Float16)v0.x; hv[1] = (_Float16)v0.y;
            hv[2] = (_Float16)v0.z; hv[3] = (_Float16)v0.w;
            hv[4] = (_Float16)v1.x; hv[5] = (_Float16)v1.y;
            hv[6] = (_Float16)v1.z; hv[7] = (_Float16)v1.w;
            *(f16x8*)&AhS[r][k8] = hv;
        }
#pragma unroll
        for (int i = 0; i < BI; ++i) {
            int n  = tid & (BN - 1);
            int kg = tid / BN;
            int k  = (i * KG + kg) << 2;
            const float* bp = B + (size_t)(kBeg + k0 + k) * ldb + col0 + n;
            f16x4 bv;
            bv[0] = (_Float16)(bp[0] * scale);
            bv[1] = (_Float16)(bp[(size_t)ldb] * scale);
            bv[2] = (_Float16)(bp[2 * (size_t)ldb] * scale);
            bv[3] = (_Float16)(bp[3 * (size_t)ldb] * scale);
            *(f16x4*)&BhS[n][k] = bv;
        }
        __syncthreads();
        f16x8 a[MF], b[NF];
#pragma unroll
        for (int m = 0; m < MF; ++m)
            a[m] = *(const f16x8*)&AhS[wm * MF * 16 + m * 16 + lr][lk * 8];
#pragma unroll
        for (int n = 0; n < NF; ++n)
            b[n] = *(const f16x8*)&BhS[wn * NF * 16 + n * 16 + lr][lk * 8];
#pragma unroll
        for (int m = 0; m < MF; ++m)
#pragma unroll
            for (int n = 0; n < NF; ++n)
                acc[m][n] = __builtin_amdgcn_mfma_f32_16x16x32_f16(a[m], b[n], acc[m][n], 0, 0, 0);
        __syncthreads();
    }

#pragma unroll
    for (int n = 0; n < NF; ++n) {
        int col = col0 + wn * NF * 16 + n * 16 + lr;
#pragma unroll
        for (int m = 0; m < MF; ++m) {
            int rbase = row0 + wm * MF * 16 + m * 16 + lk * 4;
#pragma unroll
            for (int r = 0; r < 4; ++r)
                C[(size_t)(rbase + r) * ldc + col] = acc[m][n][r] * invScale;
        }
    }
}

// sum 8 split-K partials
__global__ void reduce8(const float* __restrict__ zp, float* __restrict__ out, size_t cs) {
    size_t i = ((size_t)blockIdx.x * 256 + threadIdx.x) * 4;
    float4 a = *(const float4*)(zp + i);
#pragma unroll
    for (int c = 1; c < 8; ++c) {
        float4 b = *(const float4*)(zp + c * cs + i);
        a.x += b.x; a.y += b.y; a.z += b.z; a.w += b.w;
    }
    *(float4*)(out + i) = a;
}

// ---------------------------------------------------------------------------
// Weight preconversion -> transposed bf16 hi/lo planes, packed B-frag layout.
// ---------------------------------------------------------------------------
__launch_bounds__(256)
__global__ void wconvert(const float* __restrict__ W, ushort_t* __restrict__ Wh,
                         ushort_t* __restrict__ Wl, int Krows) {
    __shared__ float tile[32][33];
    const int k0 = blockIdx.x * 32;
    const int n0 = blockIdx.y * 32;
    const int tid = threadIdx.x;
#pragma unroll
    for (int i = 0; i < 4; ++i) {
        int idx = tid + i * 256;
        int r = idx >> 5, c = idx & 31;
        tile[r][c] = W[(size_t)(k0 + r) * 4096 + n0 + c];
    }
    __syncthreads();
    const int rn = tid >> 3;
    const int cq = (tid & 7) * 4;
    unsigned short h[4], lo[4];
#pragma unroll
    for (int j = 0; j < 4; ++j) {
        float v = tile[cq + j][rn];
        h[j]  = f2bf(v);
        lo[j] = f2bf(v - bf2f(h[j]));
    }
    const int n = n0 + rn;
    const int g = n >> 4, rr = n & 15;
    const int k = k0 + cq;
    const int K8 = Krows >> 3;
    size_t off = ((size_t)g * K8 + (k >> 3)) * 128 + rr * 8 + (k & 7);
    uint2 hp; hp.x = pack2(h[0], h[1]);  hp.y = pack2(h[2], h[3]);
    uint2 lp; lp.x = pack2(lo[0], lo[1]); lp.y = pack2(lo[2], lo[3]);
    *(uint2*)(Wh + off) = hp;
    *(uint2*)(Wl + off) = lp;
}

// ---------------------------------------------------------------------------
// LSTM step GEMM (no atomics/fences): z(64 x 4096) = A_packed @ W_packed
// + bias + optional xpart. 256 blocks x 16 z-cols; 8 waves split K 8-way,
// LDS-reduced. A is pre-packed bf16 hi/lo fragment planes (no staging).
// ---------------------------------------------------------------------------
__launch_bounds__(512)
__global__ void lstm_gemm2(const ushort_t* __restrict__ Ah, const ushort_t* __restrict__ Al,
                           const ushort_t* __restrict__ Wh, const ushort_t* __restrict__ Wl,
                           int K, const float* __restrict__ xpart,
                           const float* __restrict__ bias, float* __restrict__ z) {
    __shared__ float red[8192];
    const int tid = threadIdx.x, cg = blockIdx.x;
    const int l = tid & 63, w = tid >> 6;
    const int lr = l & 15, lk = l >> 4;
    const int K8 = K >> 3;
    const int spw = K >> 8;                          // s-steps per wave (8 waves)
    const size_t wbase = (size_t)cg * K8 * 128 + lk * 128 + lr * 8;

    f32x4 acc[4];
#pragma unroll
    for (int m = 0; m < 4; ++m)
#pragma unroll
        for (int r = 0; r < 4; ++r) acc[m][r] = 0.f;

    const int s0 = w * spw;
    for (int s = s0; s < s0 + spw; ++s) {
        bf16x8 bh = *(const bf16x8*)(Wh + wbase + (size_t)s * 512);
        bf16x8 bl = *(const bf16x8*)(Wl + wbase + (size_t)s * 512);
#pragma unroll
        for (int m = 0; m < 4; ++m) {
            size_t ao = (size_t)(s * 4 + m) * 512 + l * 8;
            bf16x8 ah = *(const bf16x8*)(Ah + ao);
            bf16x8 al = *(const bf16x8*)(Al + ao);
            acc[m] = __builtin_amdgcn_mfma_f32_16x16x32_bf16(ah, bh, acc[m], 0, 0, 0);
            acc[m] = __builtin_amdgcn_mfma_f32_16x16x32_bf16(al, bh, acc[m], 0, 0, 0);
            acc[m] = __builtin_amdgcn_mfma_f32_16x16x32_bf16(ah, bl, acc[m], 0, 0, 0);
        }
    }
#pragma unroll
    for (int m = 0; m < 4; ++m)
        *(f32x4*)&red[(w * 64 + l) * 16 + m * 4] = acc[m];
    __syncthreads();

    // write z for our 16 columns: 512 threads x 2 elems
#pragma unroll
    for (int e0 = 0; e0 < 2; ++e0) {
        int e = tid + e0 * 512;                 // 0..1023
        int r = e >> 4, c = e & 15;
        int m = r >> 4, lkr = (r >> 2) & 3, reg = r & 3;
        float v = 0.f;
#pragma unroll
        for (int ww = 0; ww < 8; ++ww)
            v += red[(ww * 64 + lkr * 16 + c) * 16 + m * 4 + reg];
        int n = cg * 16 + c;
        v += bias[n];
        if (xpart) v += xpart[(size_t)r * 4096 + n];
        z[(size_t)r * 4096 + n] = v;
    }
}

// ---------------------------------------------------------------------------
// LSTM activation: read z, update c, write h history (fp32) and packed
// bf16 hi/lo A-fragment planes for the next step GEMM(s).
// Grid 64 x 256: thread handles 4 consecutive hidden units of one row.
// ---------------------------------------------------------------------------
__launch_bounds__(256)
__global__ void lstm_act_pack(const float* __restrict__ z,
                              float* __restrict__ c_state, float* __restrict__ histF,
                              ushort_t* __restrict__ d1h, ushort_t* __restrict__ d1l, int kofs1,
                              ushort_t* __restrict__ d2h, ushort_t* __restrict__ d2l, int kofs2) {
    const int gidx = blockIdx.x * 256 + threadIdx.x;  // 0..16383
    const int r = gidx >> 8;
    const int n0 = (gidx & 255) << 2;
    float4 zf = *(const float4*)(z + (size_t)r * 4096 + n0);
    float4 zi = *(const float4*)(z + (size_t)r * 4096 + n0 + 1024);
    float4 zo = *(const float4*)(z + (size_t)r * 4096 + n0 + 2048);
    float4 zg = *(const float4*)(z + (size_t)r * 4096 + n0 + 3072);
    float4 cv = *(const float4*)(c_state + (size_t)r * 1024 + n0);
    float hn[4];
    const float* zfp = &zf.x; const float* zip = &zi.x;
    const float* zop = &zo.x; const float* zgp = &zg.x;
    float* cvp = &cv.x;
#pragma unroll
    for (int j = 0; j < 4; ++j) {
        float f = 1.f / (1.f + expf(-zfp[j]));
        float i = 1.f / (1.f + expf(-zip[j]));
        float o = 1.f / (1.f + expf(-zop[j]));
        float g = tanhf(zgp[j]);
        float cn = f * cvp[j] + i * g;
        cvp[j] = cn;
        hn[j] = o * tanhf(cn);
    }
    *(float4*)(c_state + (size_t)r * 1024 + n0) = cv;
    *(float4*)(histF + (size_t)r * 1024 + n0) = *(float4*)hn;
    unsigned short hh[4], hl[4];
#pragma unroll
    for (int j = 0; j < 4; ++j) {
        hh[j] = f2bf(hn[j]);
        hl[j] = f2bf(hn[j] - bf2f(hh[j]));
    }
    uint2 hp; hp.x = pack2(hh[0], hh[1]); hp.y = pack2(hh[2], hh[3]);
    uint2 lp; lp.x = pack2(hl[0], hl[1]); lp.y = pack2(hl[2], hl[3]);
    size_t o1 = packA_off(r, kofs1 + n0, 4);
    *(uint2*)(d1h + o1) = hp;
    *(uint2*)(d1l + o1) = lp;
    if (d2h) {
        size_t o2 = packA_off(r, kofs2 + n0, 4);
        *(uint2*)(d2h + o2) = hp;
        *(uint2*)(d2l + o2) = lp;
    }
}

// ---------------------------------------------------------------------------
// gates + gating; emits gated as packed bf16 hi/lo A-fragment planes.
// ---------------------------------------------------------------------------
__launch_bounds__(256)
__global__ void gates_gated(const float* __restrict__ h0s, const float* __restrict__ h1s,
                            const float* __restrict__ gw,
                            ushort_t* __restrict__ gAh, ushort_t* __restrict__ gAl) {
    const int r = blockIdx.x;
    const int tid = threadIdx.x;
    const float* h0r = h0s + (size_t)r * HID;
    const float* h1r = h1s + (size_t)r * HID;
    float p0 = 0.f, p1 = 0.f;
    for (int k = tid; k < HID; k += 256) {
        float v0 = h0r[k], v1 = h1r[k];
        p0 += v0 * gw[2 * k]     + v1 * gw[2 * (HID + k)];
        p1 += v0 * gw[2 * k + 1] + v1 * gw[2 * (HID + k) + 1];
    }
#pragma unroll
    for (int off = 32; off; off >>= 1) {
        p0 += __shfl_down(p0, off);
        p1 += __shfl_down(p1, off);
    }
    __shared__ float s0[4], s1[4];
    __shared__ float gg[2];
    if ((tid & 63) == 0) { s0[tid >> 6] = p0; s1[tid >> 6] = p1; }
    __syncthreads();
    if (tid == 0) {
        float a = s0[0] + s0[1] + s0[2] + s0[3];
        float b = s1[0] + s1[1] + s1[2] + s1[3];
        gg[0] = 1.f / (1.f + expf(-a));
        gg[1] = 1.f / (1.f + expf(-b));
    }
    __syncthreads();
    float g0 = gg[0], g1 = gg[1];
    const int n0 = tid * 4;
    float v[4]; unsigned short hh[4], hl[4];
#pragma unroll
    for (int j = 0; j < 4; ++j) {
        int n = n0 + j;
        v[j] = g0 * h0r[n] + g1 * h1r[n];
        hh[j] = f2bf(v[j]);
        hl[j] = f2bf(v[j] - bf2f(hh[j]));
    }
    uint2 hp; hp.x = pack2(hh[0], hh[1]); hp.y = pack2(hh[2], hh[3]);
    uint2 lp; lp.x = pack2(hl[0], hl[1]); lp.y = pack2(hl[2], hl[3]);
    size_t off = packA_off(r, n0, 256);
    *(uint2*)(gAh + off) = hp;
    *(uint2*)(gAl + off) = lp;
}

// ---------------------------------------------------------------------------
// logits GEMM: A from packed bf16 hi/lo planes (pure copy to LDS), B (outw)
// converted in LDS; BM=256 x BN=128, 8 waves, 3-term bf16 MFMA, XCD swizzle.
// ---------------------------------------------------------------------------
__launch_bounds__(512)
__global__ void gemm_out(const ushort_t* __restrict__ gAh, const ushort_t* __restrict__ gAl,
                         const float* __restrict__ Bsrc, const float* __restrict__ bias,
                         float* __restrict__ C) {
    __shared__ ushort_t AhL[8192], AlL[8192];
    __shared__ ushort_t BhS[128][40], BlS[128][40];

    const int tid = threadIdx.x;
    int lin = blockIdx.y * 250 + blockIdx.x;
    int slin = (lin & 7) * 500 + (lin >> 3);      // 4000 % 8 == 0 -> bijective
    const int bi = slin / 250, bj = slin % 250;
    const int row0 = bi * 256, col0 = bj * 128;

    const int l = tid & 63, w = tid >> 6;
    const int wm = w >> 1, wn = w & 1;
    const int lr = l & 15, lk = l >> 4;

    f32x4 acc[4][4];
#pragma unroll
    for (int m = 0; m < 4; ++m)
#pragma unroll
        for (int n = 0; n < 4; ++n)
#pragma unroll
            for (int r = 0; r < 4; ++r) acc[m][n][r] = 0.f;

    for (int k32 = 0; k32 < 32; ++k32) {
        // ---- stage A: linear copy of 2 x 16KB packed fragments ----
        const size_t chunk = ((size_t)(k32 * 256 + bi * 16)) * 512;
#pragma unroll
        for (int i = 0; i < 2; ++i) {
            int so = i * 4096 + tid * 8;
            *(uint4*)&AhL[so] = *(const uint4*)(gAh + chunk + so);
            *(uint4*)&AlL[so] = *(const uint4*)(gAl + chunk + so);
        }
        // ---- stage B: 32 x 128 fp32 -> hi/lo bf16 (coalesced) ----
#pragma unroll
        for (int i = 0; i < 2; ++i) {
            int n  = tid & 127;
            int kg = (tid >> 7) & 3;
            int k  = (i * 4 + kg) << 2;
            const float* bp = Bsrc + (size_t)(k32 * 32 + k) * VOCAB + col0 + n;
            unsigned short hh[4], hl[4];
#pragma unroll
            for (int j = 0; j < 4; ++j) {
                float v = bp[(size_t)j * VOCAB];
                hh[j] = f2bf(v);
                hl[j] = f2bf(v - bf2f(hh[j]));
            }
            uint2 hp; hp.x = pack2(hh[0], hh[1]); hp.y = pack2(hh[2], hh[3]);
            uint2 lp; lp.x = pack2(hl[0], hl[1]); lp.y = pack2(hl[2], hl[3]);
            *(uint2*)&BhS[n][k] = hp;
            *(uint2*)&BlS[n][k] = lp;
        }
        __syncthreads();
        bf16x8 ah[4], al[4], bh[4], bl[4];
#pragma unroll
        for (int m = 0; m < 4; ++m) {
            int so = (wm * 4 + m) * 512 + l * 8;
            ah[m] = *(const bf16x8*)&AhL[so];
            al[m] = *(const bf16x8*)&AlL[so];
        }
#pragma unroll
        for (int n = 0; n < 4; ++n) {
            bh[n] = *(const bf16x8*)&BhS[wn * 64 + n * 16 + lr][lk * 8];
            bl[n] = *(const bf16x8*)&BlS[wn * 64 + n * 16 + lr][lk * 8];
        }
#pragma unroll
        for (int m = 0; m < 4; ++m)
#pragma unroll
            for (int n = 0; n < 4; ++n) {
                acc[m][n] = __builtin_amdgcn_mfma_f32_16x16x32_bf16(ah[m], bh[n], acc[m][n], 0, 0, 0);
                acc[m][n] = __builtin_amdgcn_mfma_f32_16x16x32_bf16(al[m], bh[n], acc[m][n], 0, 0, 0);
                acc[m][n] = __builtin_amdgcn_mfma_f32_16x16x32_bf16(ah[m], bl[n], acc[m][n], 0, 0, 0);
            }
        __syncthreads();
    }

#pragma unroll
    for (int n = 0; n < 4; ++n) {
        int col = col0 + wn * 64 + n * 16 + lr;
        float bv = bias[col];
#pragma unroll
        for (int m = 0; m < 4; ++m) {
            int rbase = row0 + wm * 64 + m * 16 + lk * 4;
#pragma unroll
            for (int r = 0; r < 4; ++r)
                C[(size_t)(rbase + r) * VOCAB + col] = acc[m][n][r] + bv;
        }
    }
}

// ---------------------------------------------------------------------------
extern "C" void kernel_launch(void* const* d_in, const int* in_sizes, int n_in,
                              void* d_out, int out_size, void* d_ws, size_t ws_size,
                              hipStream_t stream) {
    const float* inputs = (const float*)d_in[0];
    const float* embm   = (const float*)d_in[1];
    const float* w0     = (const float*)d_in[2];
    const float* b0     = (const float*)d_in[3];
    const float* w1     = (const float*)d_in[4];
    const float* b1     = (const float*)d_in[5];
    const float* gw     = (const float*)d_in[6];
    const float* outw   = (const float*)d_in[7];
    const float* outb   = (const float*)d_in[8];
    float* logits = (float*)d_out;

    // ---- workspace layout (floats) ----
    float* ws    = (float*)d_ws;
    float* emb   = ws;                          // 2,097,152
    float* h0s   = ws + 2097152;                // 4,194,304
    float* h1s   = ws + 6291456;                // 4,194,304
    ushort_t* gAh = (ushort_t*)(ws + 10485760); // 4,194,304 shorts
    ushort_t* gAl = (ushort_t*)(ws + 12582912);
    float* zbuf  = ws + 14680064;               // 262,144
    float* c0    = ws + 14942208;               // 65,536
    float* c1    = ws + 15007744;               // 65,536
    ushort_t* hpB = (ushort_t*)(ws + 15073280); // 786,432 shorts

    ushort_t* hp0h[2] = { hpB,            hpB + 65536 };
    ushort_t* hp0l[2] = { hpB + 131072,   hpB + 196608 };
    ushort_t* hp1h[2] = { hpB + 262144,   hpB + 393216 };
    ushort_t* hp1l[2] = { hpB + 524288,   hpB + 655360 };

    // ---- d_out doubles as scratch before logits ----
    float* zpEmb = (float*)d_out;                            // 8 x 2,097,152
    float* z0x   = (float*)d_out + 16777216;                 // 16,777,216
    ushort_t* wt0h = (ushort_t*)((float*)d_out + 33554432);
    ushort_t* wt0l = wt0h + 4194304;
    ushort_t* wt1h = wt0l + 4194304;
    ushort_t* wt1l = wt1h + 8388608;

    // zero c0, c1, h packed planes (contiguous region)
    hipMemsetAsync(c0, 0, (size_t)524288 * sizeof(float), stream);

    // emb = inputs @ embm, split-K x8, fp16 single (B scaled x256)
    gemm_f16s<128, 512, 2, 4><<<dim3(1, 32, 8), 512, 0, stream>>>(
        inputs, embm, zpEmb, VOCAB, EMB, EMB, VOCAB / 8, (size_t)4096 * EMB, 256.f, 1.f / 256.f);
    reduce8<<<2048, 256, 0, stream>>>(zpEmb, emb, (size_t)4096 * EMB);

    // preconvert LSTM weights
    wconvert<<<dim3(32, 128), 256, 0, stream>>>(w0 + (size_t)512 * G4, wt0h, wt0l, 1024);
    wconvert<<<dim3(64, 128), 256, 0, stream>>>(w1, wt1h, wt1l, 2048);

    // z0x = emb @ w0[:512,:], fp16 single
    gemm_f16s<128, 128, 2, 2><<<dim3(32, 32, 1), 256, 0, stream>>>(
        emb, w0, z0x, EMB, G4, G4, EMB, 0, 256.f, 1.f / 256.f);

    // sequential LSTM: 2 dispatches per layer-step (no fences/atomics)
    for (int t = 0; t < T_STEPS; ++t) {
        int p = t & 1, q = (t + 1) & 1;
        lstm_gemm2<<<256, 512, 0, stream>>>(
            hp0h[p], hp0l[p], wt0h, wt0l, 1024,
            z0x + (size_t)t * 262144, b0, zbuf);
        lstm_act_pack<<<64, 256, 0, stream>>>(
            zbuf, c0, h0s + (size_t)t * 65536,
            hp0h[q], hp0l[q], 0, hp1h[p], hp1l[p], 0);
        lstm_gemm2<<<256, 512, 0, stream>>>(
            hp1h[p], hp1l[p], wt1h, wt1l, 2048, nullptr, b1, zbuf);
        lstm_act_pack<<<64, 256, 0, stream>>>(
            zbuf, c1, h1s + (size_t)t * 65536,
            hp1h[q], hp1l[q], 1024, nullptr, nullptr, 0);
    }

    // gating -> packed bf16 hi/lo A planes
    gates_gated<<<4096, 256, 0, stream>>>(h0s, h1s, gw, gAh, gAl);

    // logits = gated @ outw + outb
    gemm_out<<<dim3(250, 16), 512, 0, stream>>>(gAh, gAl, outw, outb, logits);
}

// Round 6
// 3096.454 us; speedup vs baseline: 2.7548x; 1.0825x over previous
//
#include <hip/hip_runtime.h>
#include <math.h>

typedef __attribute__((ext_vector_type(8))) short bf16x8;
typedef __attribute__((ext_vector_type(4))) float f32x4;
typedef __attribute__((ext_vector_type(8))) _Float16 f16x8;
typedef unsigned short ushort_t;

#define T_STEPS 64
#define BATCH   64
#define VOCAB   32000
#define EMB     512
#define HID     1024
#define G4      4096

__device__ __forceinline__ unsigned short f2bf(float x) {
    unsigned u = __builtin_bit_cast(unsigned, x);
    u += 0x7FFFu + ((u >> 16) & 1u);
    return (unsigned short)(u >> 16);
}
__device__ __forceinline__ float bf2f(unsigned short h) {
    unsigned u = ((unsigned)h) << 16;
    return __builtin_bit_cast(float, u);
}
__device__ __forceinline__ unsigned pack2(unsigned short a, unsigned short b) {
    return (unsigned)a | ((unsigned)b << 16);
}
__device__ __forceinline__ unsigned short f2h(float x) {
    return __builtin_bit_cast(unsigned short, (_Float16)x);
}

// packed A-fragment offset for 16x16x32 MFMA (M16 = row-groups of 16):
__device__ __forceinline__ size_t packA_off(int row, int k, int M16) {
    return ((size_t)((k >> 5) * M16 + (row >> 4))) * 512 +
           ((k & 31) >> 3) * 128 + (row & 15) * 8 + (k & 7);
}

// ---------------------------------------------------------------------------
// fp16 GEMM: A fp32 staged to LDS; B pre-packed fp16 fragment planes read
// DIRECTLY from global (no LDS). Split-K chunks. Used for emb and z0x.
// ---------------------------------------------------------------------------
template<int BM, int BN, int NW_M, int NW_N>
__launch_bounds__(NW_M * NW_N * 64)
__global__ void gemm_a32b16(const float* __restrict__ A, const ushort_t* __restrict__ Bp,
                            float* __restrict__ C, int lda, int ldc, int K8,
                            int KCHUNK, size_t chunkStride, float invScale) {
    constexpr int THREADS = NW_M * NW_N * 64;
    constexpr int MF = BM / NW_M / 16;
    constexpr int NF = BN / NW_N / 16;
    __shared__ _Float16 AhS[BM][40];

    const int tid  = threadIdx.x;
    const int row0 = blockIdx.y * BM;
    const int gBase = blockIdx.x * (BN / 16);
    const int kBeg = blockIdx.z * KCHUNK;
    C += (size_t)blockIdx.z * chunkStride;

    const int l = tid & 63, w = tid >> 6;
    const int wm = w / NW_N, wn = w % NW_N;
    const int lr = l & 15, lk = l >> 4;

    f32x4 acc[MF][NF];
#pragma unroll
    for (int m = 0; m < MF; ++m)
#pragma unroll
        for (int n = 0; n < NF; ++n)
#pragma unroll
            for (int r = 0; r < 4; ++r) acc[m][n][r] = 0.f;

    constexpr int AI = BM * 4 / THREADS;

    for (int k0 = 0; k0 < KCHUNK; k0 += 32) {
#pragma unroll
        for (int i = 0; i < AI; ++i) {
            int f = tid + i * THREADS;
            int r = f >> 2, k8 = (f & 3) << 3;
            const float* ap = A + (size_t)(row0 + r) * lda + kBeg + k0 + k8;
            float4 v0 = *(const float4*)ap;
            float4 v1 = *(const float4*)(ap + 4);
            f16x8 hv;
            hv[0] = (_Float16)v0.x; hv[1] = (_Float16)v0.y;
            hv[2] = (_Float16)v0.z; hv[3] = (_Float16)v0.w;
            hv[4] = (_Float16)v1.x; hv[5] = (_Float16)v1.y;
            hv[6] = (_Float16)v1.z; hv[7] = (_Float16)v1.w;
            *(f16x8*)&AhS[r][k8] = hv;
        }
        __syncthreads();
        const size_t kRow = (size_t)((kBeg + k0) >> 3) + lk;
        f16x8 a[MF], b[NF];
#pragma unroll
        for (int n = 0; n < NF; ++n) {
            int g = gBase + wn * NF + n;
            b[n] = *(const f16x8*)(Bp + ((size_t)g * K8 + kRow) * 128 + lr * 8);
        }
#pragma unroll
        for (int m = 0; m < MF; ++m)
            a[m] = *(const f16x8*)&AhS[wm * MF * 16 + m * 16 + lr][lk * 8];
#pragma unroll
        for (int m = 0; m < MF; ++m)
#pragma unroll
            for (int n = 0; n < NF; ++n)
                acc[m][n] = __builtin_amdgcn_mfma_f32_16x16x32_f16(a[m], b[n], acc[m][n], 0, 0, 0);
        __syncthreads();
    }

#pragma unroll
    for (int n = 0; n < NF; ++n) {
        int col = (gBase + wn * NF + n) * 16 + lr;
#pragma unroll
        for (int m = 0; m < MF; ++m) {
            int rbase = row0 + wm * MF * 16 + m * 16 + lk * 4;
#pragma unroll
            for (int r = 0; r < 4; ++r)
                C[(size_t)(rbase + r) * ldc + col] = acc[m][n][r] * invScale;
        }
    }
}

// sum 8 split-K partials
__global__ void reduce8(const float* __restrict__ zp, float* __restrict__ out, size_t cs) {
    size_t i = ((size_t)blockIdx.x * 256 + threadIdx.x) * 4;
    float4 a = *(const float4*)(zp + i);
#pragma unroll
    for (int c = 1; c < 8; ++c) {
        float4 b = *(const float4*)(zp + c * cs + i);
        a.x += b.x; a.y += b.y; a.z += b.z; a.w += b.w;
    }
    *(float4*)(out + i) = a;
}

// ---------------------------------------------------------------------------
// fp32 -> packed fp16 single plane (scaled). For embm and w0[:512].
// ---------------------------------------------------------------------------
__launch_bounds__(256)
__global__ void wcv16(const float* __restrict__ W, ushort_t* __restrict__ Wp,
                      int Krows, int ldW, float scale) {
    __shared__ float tile[32][33];
    const int k0 = blockIdx.x * 32;
    const int n0 = blockIdx.y * 32;
    const int tid = threadIdx.x;
#pragma unroll
    for (int i = 0; i < 4; ++i) {
        int idx = tid + i * 256;
        int r = idx >> 5, c = idx & 31;
        tile[r][c] = W[(size_t)(k0 + r) * ldW + n0 + c];
    }
    __syncthreads();
    const int rn = tid >> 3;
    const int cq = (tid & 7) * 4;
    unsigned short h[4];
#pragma unroll
    for (int j = 0; j < 4; ++j) h[j] = f2h(tile[cq + j][rn] * scale);
    const int n = n0 + rn;
    const int k = k0 + cq;
    size_t off = ((size_t)(n >> 4) * (Krows >> 3) + (k >> 3)) * 128 + (n & 15) * 8 + (k & 7);
    uint2 hp; hp.x = pack2(h[0], h[1]); hp.y = pack2(h[2], h[3]);
    *(uint2*)(Wp + off) = hp;
}

// ---------------------------------------------------------------------------
// LSTM weight conversion -> bf16 hi/lo packed planes with GATE-INTERLEAVED
// column permutation: orig col n = j*1024 + u  ->  p = (u>>2)*16 + j*4 + (u&3)
// so block cg owns all 4 gates for hidden units cg*4..cg*4+3.
// ---------------------------------------------------------------------------
__launch_bounds__(256)
__global__ void wconvert(const float* __restrict__ W, ushort_t* __restrict__ Wh,
                         ushort_t* __restrict__ Wl, int Krows) {
    __shared__ float tile[32][33];
    const int k0 = blockIdx.x * 32;
    const int n0 = blockIdx.y * 32;
    const int tid = threadIdx.x;
#pragma unroll
    for (int i = 0; i < 4; ++i) {
        int idx = tid + i * 256;
        int r = idx >> 5, c = idx & 31;
        tile[r][c] = W[(size_t)(k0 + r) * 4096 + n0 + c];
    }
    __syncthreads();
    const int rn = tid >> 3;
    const int cq = (tid & 7) * 4;
    unsigned short h[4], lo[4];
#pragma unroll
    for (int j = 0; j < 4; ++j) {
        float v = tile[cq + j][rn];
        h[j]  = f2bf(v);
        lo[j] = f2bf(v - bf2f(h[j]));
    }
    const int n = n0 + rn;                       // original column
    const int p = ((n & 1023) >> 2) * 16 + (n >> 10) * 4 + (n & 3);
    const int k = k0 + cq;
    const int K8 = Krows >> 3;
    size_t off = ((size_t)(p >> 4) * K8 + (k >> 3)) * 128 + (p & 15) * 8 + (k & 7);
    uint2 hp; hp.x = pack2(h[0], h[1]);  hp.y = pack2(h[2], h[3]);
    uint2 lp; lp.x = pack2(lo[0], lo[1]); lp.y = pack2(lo[2], lo[3]);
    *(uint2*)(Wh + off) = hp;
    *(uint2*)(Wl + off) = lp;
}

// ---------------------------------------------------------------------------
// Fused LSTM layer-step: GEMM (bf16 hi/lo x3, pre-packed A and W) + LDS
// reduce + in-block activation (thanks to gate-interleaved W columns).
// Block cg: 16 permuted z-cols = 4 gates x hidden units [cg*4, cg*4+4).
// ---------------------------------------------------------------------------
__launch_bounds__(512)
__global__ void lstm_fused(const ushort_t* __restrict__ Ah, const ushort_t* __restrict__ Al,
                           const ushort_t* __restrict__ Wh, const ushort_t* __restrict__ Wl,
                           int K, const float* __restrict__ xpart,
                           const float* __restrict__ bias,
                           float* __restrict__ c_state, float* __restrict__ histF,
                           ushort_t* __restrict__ d1h, ushort_t* __restrict__ d1l, int kofs1,
                           ushort_t* __restrict__ d2h, ushort_t* __restrict__ d2l, int kofs2) {
    __shared__ float red[512 * 20];
    const int tid = threadIdx.x, cg = blockIdx.x;
    const int l = tid & 63, w = tid >> 6;
    const int lr = l & 15, lk = l >> 4;
    const int K8 = K >> 3;
    const int spw = K >> 8;                          // 32-k steps per wave
    const size_t wbase = (size_t)cg * K8 * 128 + lk * 128 + lr * 8;

    f32x4 acc[4];
#pragma unroll
    for (int m = 0; m < 4; ++m)
#pragma unroll
        for (int r = 0; r < 4; ++r) acc[m][r] = 0.f;

    const int s0 = w * spw;
    for (int s = s0; s < s0 + spw; ++s) {
        bf16x8 bh = *(const bf16x8*)(Wh + wbase + (size_t)s * 512);
        bf16x8 bl = *(const bf16x8*)(Wl + wbase + (size_t)s * 512);
#pragma unroll
        for (int m = 0; m < 4; ++m) {
            size_t ao = (size_t)(s * 4 + m) * 512 + l * 8;
            bf16x8 ah = *(const bf16x8*)(Ah + ao);
            bf16x8 al = *(const bf16x8*)(Al + ao);
            acc[m] = __builtin_amdgcn_mfma_f32_16x16x32_bf16(ah, bh, acc[m], 0, 0, 0);
            acc[m] = __builtin_amdgcn_mfma_f32_16x16x32_bf16(al, bh, acc[m], 0, 0, 0);
            acc[m] = __builtin_amdgcn_mfma_f32_16x16x32_bf16(ah, bl, acc[m], 0, 0, 0);
        }
    }
#pragma unroll
    for (int m = 0; m < 4; ++m)
        *(f32x4*)&red[(w * 64 + l) * 20 + m * 4] = acc[m];
    __syncthreads();

    if (tid < 256) {
        const int r = tid >> 2, v = tid & 3;
        const int m = r >> 4, lkq = (r >> 2) & 3, reg = r & 3;
        const int u = cg * 4 + v;
        float z[4];
#pragma unroll
        for (int j = 0; j < 4; ++j) {
            const int c = j * 4 + v;
            float s = 0.f;
#pragma unroll
            for (int ww = 0; ww < 8; ++ww)
                s += red[(ww * 64 + lkq * 16 + c) * 20 + m * 4 + reg];
            s += bias[j * 1024 + u];
            if (xpart) s += xpart[(size_t)r * 4096 + j * 1024 + u];
            z[j] = s;
        }
        float f = 1.f / (1.f + expf(-z[0]));
        float i = 1.f / (1.f + expf(-z[1]));
        float o = 1.f / (1.f + expf(-z[2]));
        float g = tanhf(z[3]);
        const int cidx = r * 1024 + u;
        float cn = f * c_state[cidx] + i * g;
        c_state[cidx] = cn;
        float hn = o * tanhf(cn);
        histF[cidx] = hn;
        unsigned short hh = f2bf(hn);
        unsigned short hl = f2bf(hn - bf2f(hh));
        size_t o1 = packA_off(r, kofs1 + u, 4);
        d1h[o1] = hh; d1l[o1] = hl;
        if (d2h) {
            size_t o2 = packA_off(r, kofs2 + u, 4);
            d2h[o2] = hh; d2l[o2] = hl;
        }
    }
}

// ---------------------------------------------------------------------------
// gates + gating; emits gated as packed bf16 hi/lo A-fragment planes.
// ---------------------------------------------------------------------------
__launch_bounds__(256)
__global__ void gates_gated(const float* __restrict__ h0s, const float* __restrict__ h1s,
                            const float* __restrict__ gw,
                            ushort_t* __restrict__ gAh, ushort_t* __restrict__ gAl) {
    const int r = blockIdx.x;
    const int tid = threadIdx.x;
    const float* h0r = h0s + (size_t)r * HID;
    const float* h1r = h1s + (size_t)r * HID;
    float p0 = 0.f, p1 = 0.f;
    for (int k = tid; k < HID; k += 256) {
        float v0 = h0r[k], v1 = h1r[k];
        p0 += v0 * gw[2 * k]     + v1 * gw[2 * (HID + k)];
        p1 += v0 * gw[2 * k + 1] + v1 * gw[2 * (HID + k) + 1];
    }
#pragma unroll
    for (int off = 32; off; off >>= 1) {
        p0 += __shfl_down(p0, off);
        p1 += __shfl_down(p1, off);
    }
    __shared__ float s0[4], s1[4];
    __shared__ float gg[2];
    if ((tid & 63) == 0) { s0[tid >> 6] = p0; s1[tid >> 6] = p1; }
    __syncthreads();
    if (tid == 0) {
        float a = s0[0] + s0[1] + s0[2] + s0[3];
        float b = s1[0] + s1[1] + s1[2] + s1[3];
        gg[0] = 1.f / (1.f + expf(-a));
        gg[1] = 1.f / (1.f + expf(-b));
    }
    __syncthreads();
    float g0 = gg[0], g1 = gg[1];
    const int n0 = tid * 4;
    float v[4]; unsigned short hh[4], hl[4];
#pragma unroll
    for (int j = 0; j < 4; ++j) {
        int n = n0 + j;
        v[j] = g0 * h0r[n] + g1 * h1r[n];
        hh[j] = f2bf(v[j]);
        hl[j] = f2bf(v[j] - bf2f(hh[j]));
    }
    uint2 hp; hp.x = pack2(hh[0], hh[1]); hp.y = pack2(hh[2], hh[3]);
    uint2 lp; lp.x = pack2(hl[0], hl[1]); lp.y = pack2(hl[2], hl[3]);
    size_t off = packA_off(r, n0, 256);
    *(uint2*)(gAh + off) = hp;
    *(uint2*)(gAl + off) = lp;
}

// ---------------------------------------------------------------------------
// logits GEMM: BM=512 x BN=128, 16 waves; A from packed planes (linear copy),
// B (outw) converted in LDS (8 row-tiles -> half the redundant conversion).
// ---------------------------------------------------------------------------
__launch_bounds__(1024)
__global__ void gemm_out(const ushort_t* __restrict__ gAh, const ushort_t* __restrict__ gAl,
                         const float* __restrict__ Bsrc, const float* __restrict__ bias,
                         float* __restrict__ C) {
    __shared__ ushort_t AhL[16384], AlL[16384];
    __shared__ ushort_t BhS[128][40], BlS[128][40];

    const int tid = threadIdx.x;
    int lin = blockIdx.y * 250 + blockIdx.x;        // 0..1999
    int slin = (lin & 7) * 250 + (lin >> 3);        // 2000 % 8 == 0 -> bijective
    const int bi = slin / 250, bj = slin % 250;
    const int row0 = bi * 512, col0 = bj * 128;

    const int l = tid & 63, w = tid >> 6;           // 16 waves
    const int wm = w >> 1, wn = w & 1;
    const int lr = l & 15, lk = l >> 4;

    f32x4 acc[4][4];
#pragma unroll
    for (int m = 0; m < 4; ++m)
#pragma unroll
        for (int n = 0; n < 4; ++n)
#pragma unroll
            for (int r = 0; r < 4; ++r) acc[m][n][r] = 0.f;

    for (int k32 = 0; k32 < 32; ++k32) {
        // ---- stage A: linear copy of 32 row-group chunks (2 x 16 KB/plane) ----
        const size_t chunk = ((size_t)(k32 * 256 + bi * 32)) * 512;
#pragma unroll
        for (int i = 0; i < 2; ++i) {
            int so = i * 8192 + tid * 8;
            *(uint4*)&AhL[so] = *(const uint4*)(gAh + chunk + so);
            *(uint4*)&AlL[so] = *(const uint4*)(gAl + chunk + so);
        }
        // ---- stage B: 32 x 128 fp32 -> hi/lo bf16 (coalesced, one pass) ----
        {
            int n  = tid & 127;
            int kg = tid >> 7;                       // 0..7
            int k  = kg << 2;
            const float* bp = Bsrc + (size_t)(k32 * 32 + k) * VOCAB + col0 + n;
            unsigned short hh[4], hl[4];
#pragma unroll
            for (int j = 0; j < 4; ++j) {
                float v = bp[(size_t)j * VOCAB];
                hh[j] = f2bf(v);
                hl[j] = f2bf(v - bf2f(hh[j]));
            }
            uint2 hp; hp.x = pack2(hh[0], hh[1]); hp.y = pack2(hh[2], hh[3]);
            uint2 lp; lp.x = pack2(hl[0], hl[1]); lp.y = pack2(hl[2], hl[3]);
            *(uint2*)&BhS[n][k] = hp;
            *(uint2*)&BlS[n][k] = lp;
        }
        __syncthreads();
        bf16x8 ah[4], al[4], bh[4], bl[4];
#pragma unroll
        for (int m = 0; m < 4; ++m) {
            int so = (wm * 4 + m) * 512 + l * 8;
            ah[m] = *(const bf16x8*)&AhL[so];
            al[m] = *(const bf16x8*)&AlL[so];
        }
#pragma unroll
        for (int n = 0; n < 4; ++n) {
            bh[n] = *(const bf16x8*)&BhS[wn * 64 + n * 16 + lr][lk * 8];
            bl[n] = *(const bf16x8*)&BlS[wn * 64 + n * 16 + lr][lk * 8];
        }
#pragma unroll
        for (int m = 0; m < 4; ++m)
#pragma unroll
            for (int n = 0; n < 4; ++n) {
                acc[m][n] = __builtin_amdgcn_mfma_f32_16x16x32_bf16(ah[m], bh[n], acc[m][n], 0, 0, 0);
                acc[m][n] = __builtin_amdgcn_mfma_f32_16x16x32_bf16(al[m], bh[n], acc[m][n], 0, 0, 0);
                acc[m][n] = __builtin_amdgcn_mfma_f32_16x16x32_bf16(ah[m], bl[n], acc[m][n], 0, 0, 0);
            }
        __syncthreads();
    }

#pragma unroll
    for (int n = 0; n < 4; ++n) {
        int col = col0 + wn * 64 + n * 16 + lr;
        float bv = bias[col];
#pragma unroll
        for (int m = 0; m < 4; ++m) {
            int rbase = row0 + wm * 64 + m * 16 + lk * 4;
#pragma unroll
            for (int r = 0; r < 4; ++r)
                C[(size_t)(rbase + r) * VOCAB + col] = acc[m][n][r] + bv;
        }
    }
}

// ---------------------------------------------------------------------------
extern "C" void kernel_launch(void* const* d_in, const int* in_sizes, int n_in,
                              void* d_out, int out_size, void* d_ws, size_t ws_size,
                              hipStream_t stream) {
    const float* inputs = (const float*)d_in[0];
    const float* embm   = (const float*)d_in[1];
    const float* w0     = (const float*)d_in[2];
    const float* b0     = (const float*)d_in[3];
    const float* w1     = (const float*)d_in[4];
    const float* b1     = (const float*)d_in[5];
    const float* gw     = (const float*)d_in[6];
    const float* outw   = (const float*)d_in[7];
    const float* outb   = (const float*)d_in[8];
    float* logits = (float*)d_out;

    // ---- workspace layout (floats) ----
    float* ws    = (float*)d_ws;
    float* emb   = ws;                          // 2,097,152
    float* h0s   = ws + 2097152;                // 4,194,304
    float* h1s   = ws + 6291456;                // 4,194,304
    ushort_t* gAh = (ushort_t*)(ws + 10485760); // 4,194,304 shorts
    ushort_t* gAl = (ushort_t*)(ws + 12582912);
    float* c0    = ws + 14942208;               // 65,536
    float* c1    = ws + 15007744;               // 65,536
    ushort_t* hpB = (ushort_t*)(ws + 15073280); // 786,432 shorts

    ushort_t* hp0h[2] = { hpB,            hpB + 65536 };
    ushort_t* hp0l[2] = { hpB + 131072,   hpB + 196608 };
    ushort_t* hp1h[2] = { hpB + 262144,   hpB + 393216 };
    ushort_t* hp1l[2] = { hpB + 524288,   hpB + 655360 };

    // ---- d_out doubles as scratch before logits ----
    float* zpEmb = (float*)d_out;                            // 16,777,216 f
    float* z0x   = (float*)d_out + 16777216;                 // 16,777,216 f
    ushort_t* wt0h = (ushort_t*)((float*)d_out + 33554432);  // 4.2M shorts
    ushort_t* wt0l = wt0h + 4194304;
    ushort_t* wt1h = wt0l + 4194304;                         // 8.4M shorts
    ushort_t* wt1l = wt1h + 8388608;
    ushort_t* embm16 = wt1l + 8388608;                       // 16.4M shorts
    ushort_t* w0x16  = embm16 + 16384000;                    // 2.1M shorts

    // zero c0, c1, h packed planes (contiguous region)
    hipMemsetAsync(c0, 0, (size_t)524288 * sizeof(float), stream);

    // pre-convert B operands to packed fp16 planes (scaled x256)
    wcv16<<<dim3(1000, 16), 256, 0, stream>>>(embm, embm16, VOCAB, EMB, 256.f);
    wcv16<<<dim3(16, 128), 256, 0, stream>>>(w0, w0x16, EMB, G4, 256.f);

    // emb = inputs @ embm : split-K x8, B-fragments direct from global
    gemm_a32b16<128, 512, 2, 4><<<dim3(1, 32, 8), 512, 0, stream>>>(
        inputs, embm16, zpEmb, VOCAB, EMB, VOCAB / 8, VOCAB / 8, (size_t)4096 * EMB, 1.f / 256.f);
    reduce8<<<2048, 256, 0, stream>>>(zpEmb, emb, (size_t)4096 * EMB);

    // LSTM weights -> bf16 hi/lo packed planes, gate-interleaved columns
    wconvert<<<dim3(32, 128), 256, 0, stream>>>(w0 + (size_t)512 * G4, wt0h, wt0l, 1024);
    wconvert<<<dim3(64, 128), 256, 0, stream>>>(w1, wt1h, wt1l, 2048);

    // z0x = emb @ w0[:512,:]  (original column order)
    gemm_a32b16<128, 128, 2, 2><<<dim3(32, 32, 1), 256, 0, stream>>>(
        emb, w0x16, z0x, EMB, G4, EMB / 8, EMB, 0, 1.f / 256.f);

    // sequential LSTM: ONE fused dispatch per layer-step
    for (int t = 0; t < T_STEPS; ++t) {
        int p = t & 1, q = (t + 1) & 1;
        lstm_fused<<<256, 512, 0, stream>>>(
            hp0h[p], hp0l[p], wt0h, wt0l, 1024,
            z0x + (size_t)t * 262144, b0, c0, h0s + (size_t)t * 65536,
            hp0h[q], hp0l[q], 0, hp1h[p], hp1l[p], 0);
        lstm_fused<<<256, 512, 0, stream>>>(
            hp1h[p], hp1l[p], wt1h, wt1l, 2048,
            nullptr, b1, c1, h1s + (size_t)t * 65536,
            hp1h[q], hp1l[q], 1024, nullptr, nullptr, 0);
    }

    // gating -> packed bf16 hi/lo A planes
    gates_gated<<<4096, 256, 0, stream>>>(h0s, h1s, gw, gAh, gAl);

    // logits = gated @ outw + outb
    gemm_out<<<dim3(250, 8), 1024, 0, stream>>>(gAh, gAl, outw, outb, logits);
}

// Round 7
// 3013.262 us; speedup vs baseline: 2.8308x; 1.0276x over previous
//
#include <hip/hip_runtime.h>
#include <math.h>

typedef __attribute__((ext_vector_type(8))) short bf16x8;
typedef __attribute__((ext_vector_type(4))) float f32x4;
typedef __attribute__((ext_vector_type(8))) _Float16 f16x8;
typedef unsigned short ushort_t;

#define T_STEPS 64
#define BATCH   64
#define VOCAB   32000
#define EMB     512
#define HID     1024
#define G4      4096

__device__ __forceinline__ unsigned short f2bf(float x) {
    unsigned u = __builtin_bit_cast(unsigned, x);
    u += 0x7FFFu + ((u >> 16) & 1u);
    return (unsigned short)(u >> 16);
}
__device__ __forceinline__ float bf2f(unsigned short h) {
    unsigned u = ((unsigned)h) << 16;
    return __builtin_bit_cast(float, u);
}
__device__ __forceinline__ unsigned pack2(unsigned short a, unsigned short b) {
    return (unsigned)a | ((unsigned)b << 16);
}
__device__ __forceinline__ unsigned short f2h(float x) {
    return __builtin_bit_cast(unsigned short, (_Float16)x);
}

// packed A-fragment offset for 16x16x32 MFMA (M16 = row-groups of 16):
__device__ __forceinline__ size_t packA_off(int row, int k, int M16) {
    return ((size_t)((k >> 5) * M16 + (row >> 4))) * 512 +
           ((k & 31) >> 3) * 128 + (row & 15) * 8 + (k & 7);
}

// ---------------------------------------------------------------------------
// fp16 GEMM: A fp32 staged to LDS; B pre-packed fp16 fragment planes read
// DIRECTLY from global (no LDS). Split-K chunks. Used for emb and z0x.
// ---------------------------------------------------------------------------
template<int BM, int BN, int NW_M, int NW_N>
__launch_bounds__(NW_M * NW_N * 64)
__global__ void gemm_a32b16(const float* __restrict__ A, const ushort_t* __restrict__ Bp,
                            float* __restrict__ C, int lda, int ldc, int K8,
                            int KCHUNK, size_t chunkStride, float invScale) {
    constexpr int THREADS = NW_M * NW_N * 64;
    constexpr int MF = BM / NW_M / 16;
    constexpr int NF = BN / NW_N / 16;
    __shared__ _Float16 AhS[BM][40];

    const int tid  = threadIdx.x;
    const int row0 = blockIdx.y * BM;
    const int gBase = blockIdx.x * (BN / 16);
    const int kBeg = blockIdx.z * KCHUNK;
    C += (size_t)blockIdx.z * chunkStride;

    const int l = tid & 63, w = tid >> 6;
    const int wm = w / NW_N, wn = w % NW_N;
    const int lr = l & 15, lk = l >> 4;

    f32x4 acc[MF][NF];
#pragma unroll
    for (int m = 0; m < MF; ++m)
#pragma unroll
        for (int n = 0; n < NF; ++n)
#pragma unroll
            for (int r = 0; r < 4; ++r) acc[m][n][r] = 0.f;

    constexpr int AI = BM * 4 / THREADS;

    for (int k0 = 0; k0 < KCHUNK; k0 += 32) {
#pragma unroll
        for (int i = 0; i < AI; ++i) {
            int f = tid + i * THREADS;
            int r = f >> 2, k8 = (f & 3) << 3;
            const float* ap = A + (size_t)(row0 + r) * lda + kBeg + k0 + k8;
            float4 v0 = *(const float4*)ap;
            float4 v1 = *(const float4*)(ap + 4);
            f16x8 hv;
            hv[0] = (_Float16)v0.x; hv[1] = (_Float16)v0.y;
            hv[2] = (_Float16)v0.z; hv[3] = (_Float16)v0.w;
            hv[4] = (_Float16)v1.x; hv[5] = (_Float16)v1.y;
            hv[6] = (_Float16)v1.z; hv[7] = (_Float16)v1.w;
            *(f16x8*)&AhS[r][k8] = hv;
        }
        __syncthreads();
        const size_t kRow = (size_t)((kBeg + k0) >> 3) + lk;
        f16x8 a[MF], b[NF];
#pragma unroll
        for (int n = 0; n < NF; ++n) {
            int g = gBase + wn * NF + n;
            b[n] = *(const f16x8*)(Bp + ((size_t)g * K8 + kRow) * 128 + lr * 8);
        }
#pragma unroll
        for (int m = 0; m < MF; ++m)
            a[m] = *(const f16x8*)&AhS[wm * MF * 16 + m * 16 + lr][lk * 8];
#pragma unroll
        for (int m = 0; m < MF; ++m)
#pragma unroll
            for (int n = 0; n < NF; ++n)
                acc[m][n] = __builtin_amdgcn_mfma_f32_16x16x32_f16(a[m], b[n], acc[m][n], 0, 0, 0);
        __syncthreads();
    }

#pragma unroll
    for (int n = 0; n < NF; ++n) {
        int col = (gBase + wn * NF + n) * 16 + lr;
#pragma unroll
        for (int m = 0; m < MF; ++m) {
            int rbase = row0 + wm * MF * 16 + m * 16 + lk * 4;
#pragma unroll
            for (int r = 0; r < 4; ++r)
                C[(size_t)(rbase + r) * ldc + col] = acc[m][n][r] * invScale;
        }
    }
}

// sum 8 split-K partials
__global__ void reduce8(const float* __restrict__ zp, float* __restrict__ out, size_t cs) {
    size_t i = ((size_t)blockIdx.x * 256 + threadIdx.x) * 4;
    float4 a = *(const float4*)(zp + i);
#pragma unroll
    for (int c = 1; c < 8; ++c) {
        float4 b = *(const float4*)(zp + c * cs + i);
        a.x += b.x; a.y += b.y; a.z += b.z; a.w += b.w;
    }
    *(float4*)(out + i) = a;
}

// ---------------------------------------------------------------------------
// fp32 -> packed fp16 single plane (scaled). For embm and w0[:512].
// ---------------------------------------------------------------------------
__launch_bounds__(256)
__global__ void wcv16(const float* __restrict__ W, ushort_t* __restrict__ Wp,
                      int Krows, int ldW, float scale) {
    __shared__ float tile[32][33];
    const int k0 = blockIdx.x * 32;
    const int n0 = blockIdx.y * 32;
    const int tid = threadIdx.x;
#pragma unroll
    for (int i = 0; i < 4; ++i) {
        int idx = tid + i * 256;
        int r = idx >> 5, c = idx & 31;
        tile[r][c] = W[(size_t)(k0 + r) * ldW + n0 + c];
    }
    __syncthreads();
    const int rn = tid >> 3;
    const int cq = (tid & 7) * 4;
    unsigned short h[4];
#pragma unroll
    for (int j = 0; j < 4; ++j) h[j] = f2h(tile[cq + j][rn] * scale);
    const int n = n0 + rn;
    const int k = k0 + cq;
    size_t off = ((size_t)(n >> 4) * (Krows >> 3) + (k >> 3)) * 128 + (n & 15) * 8 + (k & 7);
    uint2 hp; hp.x = pack2(h[0], h[1]); hp.y = pack2(h[2], h[3]);
    *(uint2*)(Wp + off) = hp;
}

// ---------------------------------------------------------------------------
// fp32 W (Krows x N, ldW) -> transposed bf16 hi/lo packed B-fragment planes.
// PERM: gate-interleave columns (LSTM); else identity (outw).
// ---------------------------------------------------------------------------
template<bool PERM>
__launch_bounds__(256)
__global__ void wconvert_bf(const float* __restrict__ W, ushort_t* __restrict__ Wh,
                            ushort_t* __restrict__ Wl, int Krows, int ldW) {
    __shared__ float tile[32][33];
    const int k0 = blockIdx.x * 32;
    const int n0 = blockIdx.y * 32;
    const int tid = threadIdx.x;
#pragma unroll
    for (int i = 0; i < 4; ++i) {
        int idx = tid + i * 256;
        int r = idx >> 5, c = idx & 31;
        tile[r][c] = W[(size_t)(k0 + r) * ldW + n0 + c];
    }
    __syncthreads();
    const int rn = tid >> 3;
    const int cq = (tid & 7) * 4;
    unsigned short h[4], lo[4];
#pragma unroll
    for (int j = 0; j < 4; ++j) {
        float v = tile[cq + j][rn];
        h[j]  = f2bf(v);
        lo[j] = f2bf(v - bf2f(h[j]));
    }
    const int n = n0 + rn;
    const int p = PERM ? (((n & 1023) >> 2) * 16 + (n >> 10) * 4 + (n & 3)) : n;
    const int k = k0 + cq;
    const int K8 = Krows >> 3;
    size_t off = ((size_t)(p >> 4) * K8 + (k >> 3)) * 128 + (p & 15) * 8 + (k & 7);
    uint2 hp; hp.x = pack2(h[0], h[1]);  hp.y = pack2(h[2], h[3]);
    uint2 lp; lp.x = pack2(lo[0], lo[1]); lp.y = pack2(lo[2], lo[3]);
    *(uint2*)(Wh + off) = hp;
    *(uint2*)(Wl + off) = lp;
}

// ---------------------------------------------------------------------------
// LSTM fused layer-step body (GEMM + reduce + in-block activation).
// Gate-interleaved W: block cg owns 4 gates x hidden units [cg*4, cg*4+4).
// ---------------------------------------------------------------------------
__device__ __forceinline__ void lstm_body(
        float* red, int cg,
        const ushort_t* Ah, const ushort_t* Al,
        const ushort_t* Wh, const ushort_t* Wl, int K,
        const float* xpart, const float* bias,
        float* c_state, float* histF,
        ushort_t* d1h, ushort_t* d1l,
        ushort_t* d2h, ushort_t* d2l) {
    const int tid = threadIdx.x;
    const int l = tid & 63, w = tid >> 6;
    const int lr = l & 15, lk = l >> 4;
    const int K8 = K >> 3;
    const int spw = K >> 8;                          // 32-k steps per wave
    const size_t wbase = (size_t)cg * K8 * 128 + lk * 128 + lr * 8;

    f32x4 acc[4];
#pragma unroll
    for (int m = 0; m < 4; ++m)
#pragma unroll
        for (int r = 0; r < 4; ++r) acc[m][r] = 0.f;

    const int s0 = w * spw;
    for (int s = s0; s < s0 + spw; ++s) {
        bf16x8 bh = *(const bf16x8*)(Wh + wbase + (size_t)s * 512);
        bf16x8 bl = *(const bf16x8*)(Wl + wbase + (size_t)s * 512);
#pragma unroll
        for (int m = 0; m < 4; ++m) {
            size_t ao = (size_t)(s * 4 + m) * 512 + l * 8;
            bf16x8 ah = *(const bf16x8*)(Ah + ao);
            bf16x8 al = *(const bf16x8*)(Al + ao);
            acc[m] = __builtin_amdgcn_mfma_f32_16x16x32_bf16(ah, bh, acc[m], 0, 0, 0);
            acc[m] = __builtin_amdgcn_mfma_f32_16x16x32_bf16(al, bh, acc[m], 0, 0, 0);
            acc[m] = __builtin_amdgcn_mfma_f32_16x16x32_bf16(ah, bl, acc[m], 0, 0, 0);
        }
    }
#pragma unroll
    for (int m = 0; m < 4; ++m)
        *(f32x4*)&red[(w * 64 + l) * 20 + m * 4] = acc[m];
    __syncthreads();

    if (tid < 256) {
        const int r = tid >> 2, v = tid & 3;
        const int m = r >> 4, lkq = (r >> 2) & 3, reg = r & 3;
        const int u = cg * 4 + v;
        float z[4];
#pragma unroll
        for (int j = 0; j < 4; ++j) {
            const int c = j * 4 + v;
            float s = 0.f;
#pragma unroll
            for (int ww = 0; ww < 8; ++ww)
                s += red[(ww * 64 + lkq * 16 + c) * 20 + m * 4 + reg];
            s += bias[j * 1024 + u];
            if (xpart) s += xpart[(size_t)r * 4096 + j * 1024 + u];
            z[j] = s;
        }
        float f = 1.f / (1.f + expf(-z[0]));
        float i = 1.f / (1.f + expf(-z[1]));
        float o = 1.f / (1.f + expf(-z[2]));
        float g = tanhf(z[3]);
        const int cidx = r * 1024 + u;
        float cn = f * c_state[cidx] + i * g;
        c_state[cidx] = cn;
        float hn = o * tanhf(cn);
        histF[cidx] = hn;
        unsigned short hh = f2bf(hn);
        unsigned short hl = f2bf(hn - bf2f(hh));
        size_t o1 = packA_off(r, u, 4);
        d1h[o1] = hh; d1l[o1] = hl;
        if (d2h) {
            size_t o2 = packA_off(r, u, 4);
            d2h[o2] = hh; d2l[o2] = hl;
        }
    }
}

// ---------------------------------------------------------------------------
// Pipelined pair dispatch: blocks 0..255 -> layer0(t), 256..511 -> layer1(t-1)
// ---------------------------------------------------------------------------
__launch_bounds__(512)
__global__ void lstm_pair(int active0, int active1,
        // layer0(t)
        const ushort_t* Ah0, const ushort_t* Al0,
        const ushort_t* Wh0, const ushort_t* Wl0,
        const float* xpart0, const float* bias0,
        float* c0, float* hist0,
        ushort_t* d1h0, ushort_t* d1l0, ushort_t* d2h0, ushort_t* d2l0,
        // layer1(t-1)
        const ushort_t* Ah1, const ushort_t* Al1,
        const ushort_t* Wh1, const ushort_t* Wl1,
        const float* bias1, float* c1, float* hist1,
        ushort_t* d1h1, ushort_t* d1l1) {
    __shared__ float red[512 * 20];
    const int b = blockIdx.x;
    if (b < 256) {
        if (!active0) return;
        lstm_body(red, b, Ah0, Al0, Wh0, Wl0, 1024, xpart0, bias0,
                  c0, hist0, d1h0, d1l0, d2h0, d2l0);
    } else {
        if (!active1) return;
        lstm_body(red, b - 256, Ah1, Al1, Wh1, Wl1, 2048, nullptr, bias1,
                  c1, hist1, d1h1, d1l1, nullptr, nullptr);
    }
}

// ---------------------------------------------------------------------------
// gates + gating; emits gated as packed bf16 hi/lo A-fragment planes.
// ---------------------------------------------------------------------------
__launch_bounds__(256)
__global__ void gates_gated(const float* __restrict__ h0s, const float* __restrict__ h1s,
                            const float* __restrict__ gw,
                            ushort_t* __restrict__ gAh, ushort_t* __restrict__ gAl) {
    const int r = blockIdx.x;
    const int tid = threadIdx.x;
    const float* h0r = h0s + (size_t)r * HID;
    const float* h1r = h1s + (size_t)r * HID;
    float p0 = 0.f, p1 = 0.f;
    for (int k = tid; k < HID; k += 256) {
        float v0 = h0r[k], v1 = h1r[k];
        p0 += v0 * gw[2 * k]     + v1 * gw[2 * (HID + k)];
        p1 += v0 * gw[2 * k + 1] + v1 * gw[2 * (HID + k) + 1];
    }
#pragma unroll
    for (int off = 32; off; off >>= 1) {
        p0 += __shfl_down(p0, off);
        p1 += __shfl_down(p1, off);
    }
    __shared__ float s0[4], s1[4];
    __shared__ float gg[2];
    if ((tid & 63) == 0) { s0[tid >> 6] = p0; s1[tid >> 6] = p1; }
    __syncthreads();
    if (tid == 0) {
        float a = s0[0] + s0[1] + s0[2] + s0[3];
        float b = s1[0] + s1[1] + s1[2] + s1[3];
        gg[0] = 1.f / (1.f + expf(-a));
        gg[1] = 1.f / (1.f + expf(-b));
    }
    __syncthreads();
    float g0 = gg[0], g1 = gg[1];
    const int n0 = tid * 4;
    float v[4]; unsigned short hh[4], hl[4];
#pragma unroll
    for (int j = 0; j < 4; ++j) {
        int n = n0 + j;
        v[j] = g0 * h0r[n] + g1 * h1r[n];
        hh[j] = f2bf(v[j]);
        hl[j] = f2bf(v[j] - bf2f(hh[j]));
    }
    uint2 hp; hp.x = pack2(hh[0], hh[1]); hp.y = pack2(hh[2], hh[3]);
    uint2 lp; lp.x = pack2(hl[0], hl[1]); lp.y = pack2(hl[2], hl[3]);
    size_t off = packA_off(r, n0, 256);
    *(uint2*)(gAh + off) = hp;
    *(uint2*)(gAl + off) = lp;
}

// ---------------------------------------------------------------------------
// logits GEMM FAST: A from packed planes (linear LDS copy); B (outw) from
// PRE-CONVERTED packed bf16 hi/lo fragment planes, direct global reads.
// BM=256 x BN=128, 8 waves. 1-D grid 4000, XCD-chunked row-major swizzle.
// ---------------------------------------------------------------------------
__launch_bounds__(512)
__global__ void gemm_out_fast(const ushort_t* __restrict__ gAh, const ushort_t* __restrict__ gAl,
                              const ushort_t* __restrict__ Bph, const ushort_t* __restrict__ Bpl,
                              const float* __restrict__ bias, float* __restrict__ C) {
    __shared__ ushort_t AhL[8192], AlL[8192];

    const int tid = threadIdx.x;
    const int lin = (blockIdx.x & 7) * 500 + (blockIdx.x >> 3);   // 4000 blocks
    const int bi = lin / 250, bj = lin % 250;
    const int row0 = bi * 256, col0 = bj * 128;

    const int l = tid & 63, w = tid >> 6;
    const int wm = w >> 1, wn = w & 1;
    const int lr = l & 15, lk = l >> 4;

    f32x4 acc[4][4];
#pragma unroll
    for (int m = 0; m < 4; ++m)
#pragma unroll
        for (int n = 0; n < 4; ++n)
#pragma unroll
            for (int r = 0; r < 4; ++r) acc[m][n][r] = 0.f;

    for (int k32 = 0; k32 < 32; ++k32) {
        // ---- stage A: linear copy of one k32-slice of 256 rows ----
        const size_t chunk = ((size_t)(k32 * 256 + bi * 16)) * 512;
        {
            int so = tid * 8;
            *(uint4*)&AhL[so] = *(const uint4*)(gAh + chunk + so);
            *(uint4*)&AlL[so] = *(const uint4*)(gAl + chunk + so);
            so += 4096;
            *(uint4*)&AhL[so] = *(const uint4*)(gAh + chunk + so);
            *(uint4*)&AlL[so] = *(const uint4*)(gAl + chunk + so);
        }
        __syncthreads();
        // ---- B fragments direct from global (K8 = 128) ----
        bf16x8 ah[4], al[4], bh[4], bl[4];
#pragma unroll
        for (int n = 0; n < 4; ++n) {
            int g = bj * 8 + wn * 4 + n;
            size_t boff = ((size_t)g * 128 + k32 * 4 + lk) * 128 + lr * 8;
            bh[n] = *(const bf16x8*)(Bph + boff);
            bl[n] = *(const bf16x8*)(Bpl + boff);
        }
#pragma unroll
        for (int m = 0; m < 4; ++m) {
            int so = (wm * 4 + m) * 512 + l * 8;
            ah[m] = *(const bf16x8*)&AhL[so];
            al[m] = *(const bf16x8*)&AlL[so];
        }
#pragma unroll
        for (int m = 0; m < 4; ++m)
#pragma unroll
            for (int n = 0; n < 4; ++n) {
                acc[m][n] = __builtin_amdgcn_mfma_f32_16x16x32_bf16(ah[m], bh[n], acc[m][n], 0, 0, 0);
                acc[m][n] = __builtin_amdgcn_mfma_f32_16x16x32_bf16(al[m], bh[n], acc[m][n], 0, 0, 0);
                acc[m][n] = __builtin_amdgcn_mfma_f32_16x16x32_bf16(ah[m], bl[n], acc[m][n], 0, 0, 0);
            }
        __syncthreads();
    }

#pragma unroll
    for (int n = 0; n < 4; ++n) {
        int col = col0 + wn * 64 + n * 16 + lr;
        float bv = bias[col];
#pragma unroll
        for (int m = 0; m < 4; ++m) {
            int rbase = row0 + wm * 64 + m * 16 + lk * 4;
#pragma unroll
            for (int r = 0; r < 4; ++r)
                C[(size_t)(rbase + r) * VOCAB + col] = acc[m][n][r] + bv;
        }
    }
}

// ---------------------------------------------------------------------------
// logits GEMM SLOW (fallback if ws too small): round-5 version.
// ---------------------------------------------------------------------------
__launch_bounds__(512)
__global__ void gemm_out_slow(const ushort_t* __restrict__ gAh, const ushort_t* __restrict__ gAl,
                              const float* __restrict__ Bsrc, const float* __restrict__ bias,
                              float* __restrict__ C) {
    __shared__ ushort_t AhL[8192], AlL[8192];
    __shared__ ushort_t BhS[128][40], BlS[128][40];

    const int tid = threadIdx.x;
    int lin = blockIdx.y * 250 + blockIdx.x;
    int slin = (lin & 7) * 500 + (lin >> 3);
    const int bi = slin / 250, bj = slin % 250;
    const int row0 = bi * 256, col0 = bj * 128;

    const int l = tid & 63, w = tid >> 6;
    const int wm = w >> 1, wn = w & 1;
    const int lr = l & 15, lk = l >> 4;

    f32x4 acc[4][4];
#pragma unroll
    for (int m = 0; m < 4; ++m)
#pragma unroll
        for (int n = 0; n < 4; ++n)
#pragma unroll
            for (int r = 0; r < 4; ++r) acc[m][n][r] = 0.f;

    for (int k32 = 0; k32 < 32; ++k32) {
        const size_t chunk = ((size_t)(k32 * 256 + bi * 16)) * 512;
#pragma unroll
        for (int i = 0; i < 2; ++i) {
            int so = i * 4096 + tid * 8;
            *(uint4*)&AhL[so] = *(const uint4*)(gAh + chunk + so);
            *(uint4*)&AlL[so] = *(const uint4*)(gAl + chunk + so);
        }
#pragma unroll
        for (int i = 0; i < 2; ++i) {
            int n  = tid & 127;
            int kg = (tid >> 7) & 3;
            int k  = (i * 4 + kg) << 2;
            const float* bp = Bsrc + (size_t)(k32 * 32 + k) * VOCAB + col0 + n;
            unsigned short hh[4], hl[4];
#pragma unroll
            for (int j = 0; j < 4; ++j) {
                float v = bp[(size_t)j * VOCAB];
                hh[j] = f2bf(v);
                hl[j] = f2bf(v - bf2f(hh[j]));
            }
            uint2 hp; hp.x = pack2(hh[0], hh[1]); hp.y = pack2(hh[2], hh[3]);
            uint2 lp; lp.x = pack2(hl[0], hl[1]); lp.y = pack2(hl[2], hl[3]);
            *(uint2*)&BhS[n][k] = hp;
            *(uint2*)&BlS[n][k] = lp;
        }
        __syncthreads();
        bf16x8 ah[4], al[4], bh[4], bl[4];
#pragma unroll
        for (int m = 0; m < 4; ++m) {
            int so = (wm * 4 + m) * 512 + l * 8;
            ah[m] = *(const bf16x8*)&AhL[so];
            al[m] = *(const bf16x8*)&AlL[so];
        }
#pragma unroll
        for (int n = 0; n < 4; ++n) {
            bh[n] = *(const bf16x8*)&BhS[wn * 64 + n * 16 + lr][lk * 8];
            bl[n] = *(const bf16x8*)&BlS[wn * 64 + n * 16 + lr][lk * 8];
        }
#pragma unroll
        for (int m = 0; m < 4; ++m)
#pragma unroll
            for (int n = 0; n < 4; ++n) {
                acc[m][n] = __builtin_amdgcn_mfma_f32_16x16x32_bf16(ah[m], bh[n], acc[m][n], 0, 0, 0);
                acc[m][n] = __builtin_amdgcn_mfma_f32_16x16x32_bf16(al[m], bh[n], acc[m][n], 0, 0, 0);
                acc[m][n] = __builtin_amdgcn_mfma_f32_16x16x32_bf16(ah[m], bl[n], acc[m][n], 0, 0, 0);
            }
        __syncthreads();
    }

#pragma unroll
    for (int n = 0; n < 4; ++n) {
        int col = col0 + wn * 64 + n * 16 + lr;
        float bv = bias[col];
#pragma unroll
        for (int m = 0; m < 4; ++m) {
            int rbase = row0 + wm * 64 + m * 16 + lk * 4;
#pragma unroll
            for (int r = 0; r < 4; ++r)
                C[(size_t)(rbase + r) * VOCAB + col] = acc[m][n][r] + bv;
        }
    }
}

// ---------------------------------------------------------------------------
extern "C" void kernel_launch(void* const* d_in, const int* in_sizes, int n_in,
                              void* d_out, int out_size, void* d_ws, size_t ws_size,
                              hipStream_t stream) {
    const float* inputs = (const float*)d_in[0];
    const float* embm   = (const float*)d_in[1];
    const float* w0     = (const float*)d_in[2];
    const float* b0     = (const float*)d_in[3];
    const float* w1     = (const float*)d_in[4];
    const float* b1     = (const float*)d_in[5];
    const float* gw     = (const float*)d_in[6];
    const float* outw   = (const float*)d_in[7];
    const float* outb   = (const float*)d_in[8];
    float* logits = (float*)d_out;

    // ---- workspace layout (floats) ----
    float* ws    = (float*)d_ws;
    float* emb   = ws;                          // 2,097,152
    float* h0s   = ws + 2097152;                // 4,194,304
    float* h1s   = ws + 6291456;                // 4,194,304
    ushort_t* gAh = (ushort_t*)(ws + 10485760); // 4,194,304 shorts
    ushort_t* gAl = (ushort_t*)(ws + 12582912);
    float* c0    = ws + 14942208;               // 65,536
    float* c1    = ws + 15007744;               // 65,536
    ushort_t* hpB = (ushort_t*)(ws + 15073280); // 786,432 shorts
    // fast-path outw planes (131 MB) after everything else:
    ushort_t* outwH = (ushort_t*)(ws + 15466496);
    ushort_t* outwL = outwH + 32768000;
    const bool fastOut = ws_size >= (size_t)(15466496 + 32768000) * 4;

    ushort_t* hp0h[2] = { hpB,            hpB + 65536 };
    ushort_t* hp0l[2] = { hpB + 131072,   hpB + 196608 };
    ushort_t* hp1h[2] = { hpB + 262144,   hpB + 393216 };
    ushort_t* hp1l[2] = { hpB + 524288,   hpB + 655360 };

    // ---- d_out doubles as scratch before logits ----
    float* zpEmb = (float*)d_out;                            // 16,777,216 f
    float* z0x   = (float*)d_out + 16777216;                 // 16,777,216 f
    ushort_t* wt0h = (ushort_t*)((float*)d_out + 33554432);
    ushort_t* wt0l = wt0h + 4194304;
    ushort_t* wt1h = wt0l + 4194304;
    ushort_t* wt1l = wt1h + 8388608;
    ushort_t* embm16 = wt1l + 8388608;
    ushort_t* w0x16  = embm16 + 16384000;

    // zero c0, c1, h packed planes (contiguous region)
    hipMemsetAsync(c0, 0, (size_t)524288 * sizeof(float), stream);

    // pre-convert B operands to packed fp16 planes (scaled x256)
    wcv16<<<dim3(1000, 16), 256, 0, stream>>>(embm, embm16, VOCAB, EMB, 256.f);
    wcv16<<<dim3(16, 128), 256, 0, stream>>>(w0, w0x16, EMB, G4, 256.f);

    // emb = inputs @ embm : split-K x8, B-fragments direct from global
    gemm_a32b16<128, 512, 2, 4><<<dim3(1, 32, 8), 512, 0, stream>>>(
        inputs, embm16, zpEmb, VOCAB, EMB, VOCAB / 8, VOCAB / 8, (size_t)4096 * EMB, 1.f / 256.f);
    reduce8<<<2048, 256, 0, stream>>>(zpEmb, emb, (size_t)4096 * EMB);

    // LSTM weights -> bf16 hi/lo packed planes, gate-interleaved columns
    wconvert_bf<true><<<dim3(32, 128), 256, 0, stream>>>(w0 + (size_t)512 * G4, wt0h, wt0l, 1024, G4);
    wconvert_bf<true><<<dim3(64, 128), 256, 0, stream>>>(w1, wt1h, wt1l, 2048, G4);

    // outw -> packed bf16 hi/lo planes (fast path only)
    if (fastOut)
        wconvert_bf<false><<<dim3(32, 1000), 256, 0, stream>>>(outw, outwH, outwL, 1024, VOCAB);

    // z0x = emb @ w0[:512,:]  (original column order)
    gemm_a32b16<128, 128, 2, 2><<<dim3(32, 32, 1), 256, 0, stream>>>(
        emb, w0x16, z0x, EMB, G4, EMB / 8, EMB, 0, 1.f / 256.f);

    // pipelined LSTM: dispatch t runs layer0(t) || layer1(t-1); 65 dispatches
    for (int t = 0; t <= T_STEPS; ++t) {
        const int p0 = t & 1, q0 = (t + 1) & 1;
        const int s  = t - 1, ss = s < 0 ? 0 : s;
        const int p1 = ss & 1, q1 = (ss + 1) & 1;
        lstm_pair<<<512, 512, 0, stream>>>(
            (t < T_STEPS) ? 1 : 0, (t >= 1) ? 1 : 0,
            // layer0(t)
            hp0h[p0], hp0l[p0], wt0h, wt0l,
            z0x + (size_t)(t < T_STEPS ? t : 0) * 262144, b0,
            c0, h0s + (size_t)(t < T_STEPS ? t : 0) * 65536,
            hp0h[q0], hp0l[q0], hp1h[p0], hp1l[p0],
            // layer1(s)
            hp1h[p1], hp1l[p1], wt1h, wt1l,
            b1, c1, h1s + (size_t)ss * 65536,
            hp1h[q1] + 65536, hp1l[q1] + 65536);
    }

    // gating -> packed bf16 hi/lo A planes
    gates_gated<<<4096, 256, 0, stream>>>(h0s, h1s, gw, gAh, gAl);

    // logits = gated @ outw + outb
    if (fastOut)
        gemm_out_fast<<<4000, 512, 0, stream>>>(gAh, gAl, outwH, outwL, outb, logits);
    else
        gemm_out_slow<<<dim3(250, 16), 512, 0, stream>>>(gAh, gAl, outw, outb, logits);
}

// Round 8
// 2174.104 us; speedup vs baseline: 3.9235x; 1.3860x over previous
//
#include <hip/hip_runtime.h>
#include <math.h>

typedef __attribute__((ext_vector_type(8))) short bf16x8;
typedef __attribute__((ext_vector_type(4))) float f32x4;
typedef __attribute__((ext_vector_type(8))) _Float16 f16x8;
typedef unsigned short ushort_t;

#define T_STEPS 64
#define BATCH   64
#define VOCAB   32000
#define EMB     512
#define HID     1024
#define G4      4096

__device__ __forceinline__ unsigned short f2bf(float x) {
    unsigned u = __builtin_bit_cast(unsigned, x);
    u += 0x7FFFu + ((u >> 16) & 1u);
    return (unsigned short)(u >> 16);
}
__device__ __forceinline__ float bf2f(unsigned short h) {
    unsigned u = ((unsigned)h) << 16;
    return __builtin_bit_cast(float, u);
}
__device__ __forceinline__ unsigned pack2(unsigned short a, unsigned short b) {
    return (unsigned)a | ((unsigned)b << 16);
}
__device__ __forceinline__ unsigned short f2h(float x) {
    return __builtin_bit_cast(unsigned short, (_Float16)x);
}

// packed A-fragment offset for 16x16x32 MFMA (M16 = row-groups of 16):
__device__ __forceinline__ size_t packA_off(int row, int k, int M16) {
    return ((size_t)((k >> 5) * M16 + (row >> 4))) * 512 +
           ((k & 31) >> 3) * 128 + (row & 15) * 8 + (k & 7);
}

// ---------------------------------------------------------------------------
// fp16 GEMM: A fp32 staged to LDS; B pre-packed fp16 fragment planes read
// DIRECTLY from global (no LDS). Split-K chunks. Used for emb and z0x.
// ---------------------------------------------------------------------------
template<int BM, int BN, int NW_M, int NW_N>
__launch_bounds__(NW_M * NW_N * 64)
__global__ void gemm_a32b16(const float* __restrict__ A, const ushort_t* __restrict__ Bp,
                            float* __restrict__ C, int lda, int ldc, int K8,
                            int KCHUNK, size_t chunkStride, float invScale) {
    constexpr int THREADS = NW_M * NW_N * 64;
    constexpr int MF = BM / NW_M / 16;
    constexpr int NF = BN / NW_N / 16;
    __shared__ _Float16 AhS[BM][40];

    const int tid  = threadIdx.x;
    const int row0 = blockIdx.y * BM;
    const int gBase = blockIdx.x * (BN / 16);
    const int kBeg = blockIdx.z * KCHUNK;
    C += (size_t)blockIdx.z * chunkStride;

    const int l = tid & 63, w = tid >> 6;
    const int wm = w / NW_N, wn = w % NW_N;
    const int lr = l & 15, lk = l >> 4;

    f32x4 acc[MF][NF];
#pragma unroll
    for (int m = 0; m < MF; ++m)
#pragma unroll
        for (int n = 0; n < NF; ++n)
#pragma unroll
            for (int r = 0; r < 4; ++r) acc[m][n][r] = 0.f;

    constexpr int AI = BM * 4 / THREADS;

    for (int k0 = 0; k0 < KCHUNK; k0 += 32) {
#pragma unroll
        for (int i = 0; i < AI; ++i) {
            int f = tid + i * THREADS;
            int r = f >> 2, k8 = (f & 3) << 3;
            const float* ap = A + (size_t)(row0 + r) * lda + kBeg + k0 + k8;
            float4 v0 = *(const float4*)ap;
            float4 v1 = *(const float4*)(ap + 4);
            f16x8 hv;
            hv[0] = (_Float16)v0.x; hv[1] = (_Float16)v0.y;
            hv[2] = (_Float16)v0.z; hv[3] = (_Float16)v0.w;
            hv[4] = (_Float16)v1.x; hv[5] = (_Float16)v1.y;
            hv[6] = (_Float16)v1.z; hv[7] = (_Float16)v1.w;
            *(f16x8*)&AhS[r][k8] = hv;
        }
        __syncthreads();
        const size_t kRow = (size_t)((kBeg + k0) >> 3) + lk;
        f16x8 a[MF], b[NF];
#pragma unroll
        for (int n = 0; n < NF; ++n) {
            int g = gBase + wn * NF + n;
            b[n] = *(const f16x8*)(Bp + ((size_t)g * K8 + kRow) * 128 + lr * 8);
        }
#pragma unroll
        for (int m = 0; m < MF; ++m)
            a[m] = *(const f16x8*)&AhS[wm * MF * 16 + m * 16 + lr][lk * 8];
#pragma unroll
        for (int m = 0; m < MF; ++m)
#pragma unroll
            for (int n = 0; n < NF; ++n)
                acc[m][n] = __builtin_amdgcn_mfma_f32_16x16x32_f16(a[m], b[n], acc[m][n], 0, 0, 0);
        __syncthreads();
    }

#pragma unroll
    for (int n = 0; n < NF; ++n) {
        int col = (gBase + wn * NF + n) * 16 + lr;
#pragma unroll
        for (int m = 0; m < MF; ++m) {
            int rbase = row0 + wm * MF * 16 + m * 16 + lk * 4;
#pragma unroll
            for (int r = 0; r < 4; ++r)
                C[(size_t)(rbase + r) * ldc + col] = acc[m][n][r] * invScale;
        }
    }
}

// sum 8 split-K partials
__global__ void reduce8(const float* __restrict__ zp, float* __restrict__ out, size_t cs) {
    size_t i = ((size_t)blockIdx.x * 256 + threadIdx.x) * 4;
    float4 a = *(const float4*)(zp + i);
#pragma unroll
    for (int c = 1; c < 8; ++c) {
        float4 b = *(const float4*)(zp + c * cs + i);
        a.x += b.x; a.y += b.y; a.z += b.z; a.w += b.w;
    }
    *(float4*)(out + i) = a;
}

// ---------------------------------------------------------------------------
// fp32 -> packed fp16 single plane (scaled). For embm, w0[:512], outw.
// ---------------------------------------------------------------------------
__launch_bounds__(256)
__global__ void wcv16(const float* __restrict__ W, ushort_t* __restrict__ Wp,
                      int Krows, int ldW, float scale) {
    __shared__ float tile[32][33];
    const int k0 = blockIdx.x * 32;
    const int n0 = blockIdx.y * 32;
    const int tid = threadIdx.x;
#pragma unroll
    for (int i = 0; i < 4; ++i) {
        int idx = tid + i * 256;
        int r = idx >> 5, c = idx & 31;
        tile[r][c] = W[(size_t)(k0 + r) * ldW + n0 + c];
    }
    __syncthreads();
    const int rn = tid >> 3;
    const int cq = (tid & 7) * 4;
    unsigned short h[4];
#pragma unroll
    for (int j = 0; j < 4; ++j) h[j] = f2h(tile[cq + j][rn] * scale);
    const int n = n0 + rn;
    const int k = k0 + cq;
    size_t off = ((size_t)(n >> 4) * (Krows >> 3) + (k >> 3)) * 128 + (n & 15) * 8 + (k & 7);
    uint2 hp; hp.x = pack2(h[0], h[1]); hp.y = pack2(h[2], h[3]);
    *(uint2*)(Wp + off) = hp;
}

// ---------------------------------------------------------------------------
// fp32 W (Krows x N, ldW) -> transposed bf16 hi/lo packed B-fragment planes.
// PERM: gate-interleave columns (LSTM).
// ---------------------------------------------------------------------------
template<bool PERM>
__launch_bounds__(256)
__global__ void wconvert_bf(const float* __restrict__ W, ushort_t* __restrict__ Wh,
                            ushort_t* __restrict__ Wl, int Krows, int ldW) {
    __shared__ float tile[32][33];
    const int k0 = blockIdx.x * 32;
    const int n0 = blockIdx.y * 32;
    const int tid = threadIdx.x;
#pragma unroll
    for (int i = 0; i < 4; ++i) {
        int idx = tid + i * 256;
        int r = idx >> 5, c = idx & 31;
        tile[r][c] = W[(size_t)(k0 + r) * ldW + n0 + c];
    }
    __syncthreads();
    const int rn = tid >> 3;
    const int cq = (tid & 7) * 4;
    unsigned short h[4], lo[4];
#pragma unroll
    for (int j = 0; j < 4; ++j) {
        float v = tile[cq + j][rn];
        h[j]  = f2bf(v);
        lo[j] = f2bf(v - bf2f(h[j]));
    }
    const int n = n0 + rn;
    const int p = PERM ? (((n & 1023) >> 2) * 16 + (n >> 10) * 4 + (n & 3)) : n;
    const int k = k0 + cq;
    const int K8 = Krows >> 3;
    size_t off = ((size_t)(p >> 4) * K8 + (k >> 3)) * 128 + (p & 15) * 8 + (k & 7);
    uint2 hp; hp.x = pack2(h[0], h[1]);  hp.y = pack2(h[2], h[3]);
    uint2 lp; lp.x = pack2(lo[0], lo[1]); lp.y = pack2(lo[2], lo[3]);
    *(uint2*)(Wh + off) = hp;
    *(uint2*)(Wl + off) = lp;
}

// ---------------------------------------------------------------------------
// LSTM fused layer-step body (GEMM + reduce + in-block activation).
// ---------------------------------------------------------------------------
__device__ __forceinline__ void lstm_body(
        float* red, int cg,
        const ushort_t* Ah, const ushort_t* Al,
        const ushort_t* Wh, const ushort_t* Wl, int K,
        const float* xpart, const float* bias,
        float* c_state, float* histF,
        ushort_t* d1h, ushort_t* d1l,
        ushort_t* d2h, ushort_t* d2l) {
    const int tid = threadIdx.x;
    const int l = tid & 63, w = tid >> 6;
    const int lr = l & 15, lk = l >> 4;
    const int K8 = K >> 3;
    const int spw = K >> 8;
    const size_t wbase = (size_t)cg * K8 * 128 + lk * 128 + lr * 8;

    f32x4 acc[4];
#pragma unroll
    for (int m = 0; m < 4; ++m)
#pragma unroll
        for (int r = 0; r < 4; ++r) acc[m][r] = 0.f;

    const int s0 = w * spw;
    for (int s = s0; s < s0 + spw; ++s) {
        bf16x8 bh = *(const bf16x8*)(Wh + wbase + (size_t)s * 512);
        bf16x8 bl = *(const bf16x8*)(Wl + wbase + (size_t)s * 512);
#pragma unroll
        for (int m = 0; m < 4; ++m) {
            size_t ao = (size_t)(s * 4 + m) * 512 + l * 8;
            bf16x8 ah = *(const bf16x8*)(Ah + ao);
            bf16x8 al = *(const bf16x8*)(Al + ao);
            acc[m] = __builtin_amdgcn_mfma_f32_16x16x32_bf16(ah, bh, acc[m], 0, 0, 0);
            acc[m] = __builtin_amdgcn_mfma_f32_16x16x32_bf16(al, bh, acc[m], 0, 0, 0);
            acc[m] = __builtin_amdgcn_mfma_f32_16x16x32_bf16(ah, bl, acc[m], 0, 0, 0);
        }
    }
#pragma unroll
    for (int m = 0; m < 4; ++m)
        *(f32x4*)&red[(w * 64 + l) * 20 + m * 4] = acc[m];
    __syncthreads();

    if (tid < 256) {
        const int r = tid >> 2, v = tid & 3;
        const int m = r >> 4, lkq = (r >> 2) & 3, reg = r & 3;
        const int u = cg * 4 + v;
        float z[4];
#pragma unroll
        for (int j = 0; j < 4; ++j) {
            const int c = j * 4 + v;
            float s = 0.f;
#pragma unroll
            for (int ww = 0; ww < 8; ++ww)
                s += red[(ww * 64 + lkq * 16 + c) * 20 + m * 4 + reg];
            s += bias[j * 1024 + u];
            if (xpart) s += xpart[(size_t)r * 4096 + j * 1024 + u];
            z[j] = s;
        }
        float f = 1.f / (1.f + expf(-z[0]));
        float i = 1.f / (1.f + expf(-z[1]));
        float o = 1.f / (1.f + expf(-z[2]));
        float g = tanhf(z[3]);
        const int cidx = r * 1024 + u;
        float cn = f * c_state[cidx] + i * g;
        c_state[cidx] = cn;
        float hn = o * tanhf(cn);
        histF[cidx] = hn;
        unsigned short hh = f2bf(hn);
        unsigned short hl = f2bf(hn - bf2f(hh));
        size_t o1 = packA_off(r, u, 4);
        d1h[o1] = hh; d1l[o1] = hl;
        if (d2h) {
            size_t o2 = packA_off(r, u, 4);
            d2h[o2] = hh; d2l[o2] = hl;
        }
    }
}

// ---------------------------------------------------------------------------
// Pipelined pair dispatch: blocks 0..255 -> layer0(t), 256..511 -> layer1(t-1)
// ---------------------------------------------------------------------------
__launch_bounds__(512)
__global__ void lstm_pair(int active0, int active1,
        const ushort_t* Ah0, const ushort_t* Al0,
        const ushort_t* Wh0, const ushort_t* Wl0,
        const float* xpart0, const float* bias0,
        float* c0, float* hist0,
        ushort_t* d1h0, ushort_t* d1l0, ushort_t* d2h0, ushort_t* d2l0,
        const ushort_t* Ah1, const ushort_t* Al1,
        const ushort_t* Wh1, const ushort_t* Wl1,
        const float* bias1, float* c1, float* hist1,
        ushort_t* d1h1, ushort_t* d1l1) {
    __shared__ float red[512 * 20];
    const int b = blockIdx.x;
    if (b < 256) {
        if (!active0) return;
        lstm_body(red, b, Ah0, Al0, Wh0, Wl0, 1024, xpart0, bias0,
                  c0, hist0, d1h0, d1l0, d2h0, d2l0);
    } else {
        if (!active1) return;
        lstm_body(red, b - 256, Ah1, Al1, Wh1, Wl1, 2048, nullptr, bias1,
                  c1, hist1, d1h1, d1l1, nullptr, nullptr);
    }
}

// ---------------------------------------------------------------------------
// gates + gating; emits gated as packed fp16 SINGLE A-fragment plane (x256).
// ---------------------------------------------------------------------------
__launch_bounds__(256)
__global__ void gates_gated(const float* __restrict__ h0s, const float* __restrict__ h1s,
                            const float* __restrict__ gw,
                            ushort_t* __restrict__ gA16) {
    const int r = blockIdx.x;
    const int tid = threadIdx.x;
    const float* h0r = h0s + (size_t)r * HID;
    const float* h1r = h1s + (size_t)r * HID;
    float p0 = 0.f, p1 = 0.f;
    for (int k = tid; k < HID; k += 256) {
        float v0 = h0r[k], v1 = h1r[k];
        p0 += v0 * gw[2 * k]     + v1 * gw[2 * (HID + k)];
        p1 += v0 * gw[2 * k + 1] + v1 * gw[2 * (HID + k) + 1];
    }
#pragma unroll
    for (int off = 32; off; off >>= 1) {
        p0 += __shfl_down(p0, off);
        p1 += __shfl_down(p1, off);
    }
    __shared__ float s0[4], s1[4];
    __shared__ float gg[2];
    if ((tid & 63) == 0) { s0[tid >> 6] = p0; s1[tid >> 6] = p1; }
    __syncthreads();
    if (tid == 0) {
        float a = s0[0] + s0[1] + s0[2] + s0[3];
        float b = s1[0] + s1[1] + s1[2] + s1[3];
        gg[0] = 1.f / (1.f + expf(-a));
        gg[1] = 1.f / (1.f + expf(-b));
    }
    __syncthreads();
    float g0 = gg[0], g1 = gg[1];
    const int n0 = tid * 4;
    unsigned short h[4];
#pragma unroll
    for (int j = 0; j < 4; ++j) {
        int n = n0 + j;
        h[j] = f2h((g0 * h0r[n] + g1 * h1r[n]) * 256.f);
    }
    uint2 hp; hp.x = pack2(h[0], h[1]); hp.y = pack2(h[2], h[3]);
    *(uint2*)(gA16 + packA_off(r, n0, 256)) = hp;
}

// ---------------------------------------------------------------------------
// logits GEMM v4: fp16 single planes both sides (pre-packed), double-buffered
// LDS with register prefetch pipeline, 16 MFMA/iter, one barrier/iter.
// BM=256 x BN=128, 8 waves, grid 4000 XCD-swizzled.
// ---------------------------------------------------------------------------
__launch_bounds__(512)
__global__ void gemm_out_v4(const ushort_t* __restrict__ gA16, const ushort_t* __restrict__ Bp,
                            const float* __restrict__ bias, float* __restrict__ C) {
    __shared__ ushort_t AL[2][8192];
    __shared__ ushort_t BL[2][4096];

    const int tid = threadIdx.x;
    const int lin = (blockIdx.x & 7) * 500 + (blockIdx.x >> 3);   // 4000 % 8 == 0
    const int bi = lin / 250, bj = lin % 250;
    const int row0 = bi * 256, col0 = bj * 128;

    const int l = tid & 63, w = tid >> 6;
    const int wm = w >> 1, wn = w & 1;
    const int lr = l & 15, lk = l >> 4;

    const int aOff = tid * 8;                                 // shorts
    const size_t bBase = (size_t)(bj * 8 + (tid >> 6)) * 16384 + (tid & 63) * 8;

    f32x4 acc[4][4];
#pragma unroll
    for (int m = 0; m < 4; ++m)
#pragma unroll
        for (int n = 0; n < 4; ++n)
#pragma unroll
            for (int r = 0; r < 4; ++r) acc[m][n][r] = 0.f;

    // prologue: stage tile 0
    {
        const size_t cA = ((size_t)(0 * 256 + bi * 16)) * 512;
        uint4 a0 = *(const uint4*)(gA16 + cA + aOff);
        uint4 a1 = *(const uint4*)(gA16 + cA + 4096 + aOff);
        uint4 b0 = *(const uint4*)(Bp + bBase);
        *(uint4*)&AL[0][aOff] = a0;
        *(uint4*)&AL[0][4096 + aOff] = a1;
        *(uint4*)&BL[0][aOff & 4095] = b0;
    }
    __syncthreads();

    uint4 rA0, rA1, rB;
    for (int k32 = 0; k32 < 32; ++k32) {
        const int cur = k32 & 1, nxt = cur ^ 1;
        const bool hasNext = (k32 < 31);
        if (hasNext) {
            const size_t cA = ((size_t)((k32 + 1) * 256 + bi * 16)) * 512;
            rA0 = *(const uint4*)(gA16 + cA + aOff);
            rA1 = *(const uint4*)(gA16 + cA + 4096 + aOff);
            rB  = *(const uint4*)(Bp + bBase + (size_t)(k32 + 1) * 512);
        }
        f16x8 a[4], b[4];
#pragma unroll
        for (int m = 0; m < 4; ++m)
            a[m] = *(const f16x8*)&AL[cur][(wm * 4 + m) * 512 + l * 8];
#pragma unroll
        for (int n = 0; n < 4; ++n)
            b[n] = *(const f16x8*)&BL[cur][(wn * 4 + n) * 512 + l * 8];
#pragma unroll
        for (int m = 0; m < 4; ++m)
#pragma unroll
            for (int n = 0; n < 4; ++n)
                acc[m][n] = __builtin_amdgcn_mfma_f32_16x16x32_f16(a[m], b[n], acc[m][n], 0, 0, 0);
        if (hasNext) {
            *(uint4*)&AL[nxt][aOff] = rA0;
            *(uint4*)&AL[nxt][4096 + aOff] = rA1;
            *(uint4*)&BL[nxt][aOff & 4095] = rB;
        }
        __syncthreads();
    }

    constexpr float invScale = 1.f / 65536.f;
#pragma unroll
    for (int n = 0; n < 4; ++n) {
        int col = col0 + wn * 64 + n * 16 + lr;
        float bv = bias[col];
#pragma unroll
        for (int m = 0; m < 4; ++m) {
            int rbase = row0 + wm * 64 + m * 16 + lk * 4;
#pragma unroll
            for (int r = 0; r < 4; ++r)
                C[(size_t)(rbase + r) * VOCAB + col] = acc[m][n][r] * invScale + bv;
        }
    }
}

// ---------------------------------------------------------------------------
extern "C" void kernel_launch(void* const* d_in, const int* in_sizes, int n_in,
                              void* d_out, int out_size, void* d_ws, size_t ws_size,
                              hipStream_t stream) {
    const float* inputs = (const float*)d_in[0];
    const float* embm   = (const float*)d_in[1];
    const float* w0     = (const float*)d_in[2];
    const float* b0     = (const float*)d_in[3];
    const float* w1     = (const float*)d_in[4];
    const float* b1     = (const float*)d_in[5];
    const float* gw     = (const float*)d_in[6];
    const float* outw   = (const float*)d_in[7];
    const float* outb   = (const float*)d_in[8];
    float* logits = (float*)d_out;

    // ---- workspace layout (floats) ----
    float* ws    = (float*)d_ws;
    float* emb   = ws;                          // 2,097,152
    float* h0s   = ws + 2097152;                // 4,194,304
    float* h1s   = ws + 6291456;                // 4,194,304
    ushort_t* gA16 = (ushort_t*)(ws + 10485760); // 4,194,304 shorts (2,097,152 f)
    float* c0    = ws + 14942208;               // 65,536
    float* c1    = ws + 15007744;               // 65,536
    ushort_t* hpB = (ushort_t*)(ws + 15073280); // 786,432 shorts
    ushort_t* outw16 = (ushort_t*)(ws + 15466496); // 32,768,000 shorts (65.5 MB)

    ushort_t* hp0h[2] = { hpB,            hpB + 65536 };
    ushort_t* hp0l[2] = { hpB + 131072,   hpB + 196608 };
    ushort_t* hp1h[2] = { hpB + 262144,   hpB + 393216 };
    ushort_t* hp1l[2] = { hpB + 524288,   hpB + 655360 };

    // ---- d_out doubles as scratch before logits ----
    float* zpEmb = (float*)d_out;                            // 16,777,216 f
    float* z0x   = (float*)d_out + 16777216;                 // 16,777,216 f
    ushort_t* wt0h = (ushort_t*)((float*)d_out + 33554432);
    ushort_t* wt0l = wt0h + 4194304;
    ushort_t* wt1h = wt0l + 4194304;
    ushort_t* wt1l = wt1h + 8388608;
    ushort_t* embm16 = wt1l + 8388608;
    ushort_t* w0x16  = embm16 + 16384000;

    // zero c0, c1, h packed planes (contiguous region)
    hipMemsetAsync(c0, 0, (size_t)524288 * sizeof(float), stream);

    // pre-convert B operands to packed fp16 planes (scaled x256)
    wcv16<<<dim3(1000, 16), 256, 0, stream>>>(embm, embm16, VOCAB, EMB, 256.f);
    wcv16<<<dim3(16, 128), 256, 0, stream>>>(w0, w0x16, EMB, G4, 256.f);
    wcv16<<<dim3(32, 1000), 256, 0, stream>>>(outw, outw16, HID, VOCAB, 256.f);

    // emb = inputs @ embm : split-K x8, B-fragments direct from global
    gemm_a32b16<128, 512, 2, 4><<<dim3(1, 32, 8), 512, 0, stream>>>(
        inputs, embm16, zpEmb, VOCAB, EMB, VOCAB / 8, VOCAB / 8, (size_t)4096 * EMB, 1.f / 256.f);
    reduce8<<<2048, 256, 0, stream>>>(zpEmb, emb, (size_t)4096 * EMB);

    // LSTM weights -> bf16 hi/lo packed planes, gate-interleaved columns
    wconvert_bf<true><<<dim3(32, 128), 256, 0, stream>>>(w0 + (size_t)512 * G4, wt0h, wt0l, 1024, G4);
    wconvert_bf<true><<<dim3(64, 128), 256, 0, stream>>>(w1, wt1h, wt1l, 2048, G4);

    // z0x = emb @ w0[:512,:]  (original column order)
    gemm_a32b16<128, 128, 2, 2><<<dim3(32, 32, 1), 256, 0, stream>>>(
        emb, w0x16, z0x, EMB, G4, EMB / 8, EMB, 0, 1.f / 256.f);

    // pipelined LSTM: dispatch t runs layer0(t) || layer1(t-1); 65 dispatches
    for (int t = 0; t <= T_STEPS; ++t) {
        const int p0 = t & 1, q0 = (t + 1) & 1;
        const int s  = t - 1, ss = s < 0 ? 0 : s;
        const int p1 = ss & 1, q1 = (ss + 1) & 1;
        lstm_pair<<<512, 512, 0, stream>>>(
            (t < T_STEPS) ? 1 : 0, (t >= 1) ? 1 : 0,
            hp0h[p0], hp0l[p0], wt0h, wt0l,
            z0x + (size_t)(t < T_STEPS ? t : 0) * 262144, b0,
            c0, h0s + (size_t)(t < T_STEPS ? t : 0) * 65536,
            hp0h[q0], hp0l[q0], hp1h[p0], hp1l[p0],
            hp1h[p1], hp1l[p1], wt1h, wt1l,
            b1, c1, h1s + (size_t)ss * 65536,
            hp1h[q1] + 65536, hp1l[q1] + 65536);
    }

    // gating -> packed fp16 single A plane (x256)
    gates_gated<<<4096, 256, 0, stream>>>(h0s, h1s, gw, gA16);

    // logits = gated @ outw + outb  (fp16 single both sides)
    gemm_out_v4<<<4000, 512, 0, stream>>>(gA16, outw16, outb, logits);
}